// Round 1
// 309.262 us; speedup vs baseline: 1.0354x; 1.0354x over previous
//
#include <hip/hip_runtime.h>
#include <hip/hip_bf16.h>

#define L 2048
#define D 2048
#define NH 32
#define NKV 8
#define HD 64

typedef unsigned short u16;
typedef __attribute__((ext_vector_type(8))) short bf16x8;   // 8 bf16 in 4 VGPRs
typedef __attribute__((ext_vector_type(4))) float f32x4;

#define QSCALE 0.1803368801f   // 0.125 * log2(e): S comes out in log2 domain

__device__ __forceinline__ u16 f2bf(float x) {
    __hip_bfloat16 b = __float2bfloat16(x);
    return *reinterpret_cast<u16*>(&b);
}

// Async global->LDS, 16B per lane. HW semantics: wave-uniform base (first
// lane's ptr) + lane*16; our layouts are lane-order contiguous to match.
__device__ __forceinline__ void gload_lds16(const void* g, void* l) {
    __builtin_amdgcn_global_load_lds(
        (const __attribute__((address_space(1))) unsigned int*)g,
        (__attribute__((address_space(3))) unsigned int*)l, 16, 0, 0);
}

// ---------------------------------------------------------------------------
// x fp32 -> bf16, float4-vectorized.
// ---------------------------------------------------------------------------
__global__ void cast_x_kernel(const float* __restrict__ in, u16* __restrict__ out, int n4)
{
    int i = blockIdx.x * 256 + threadIdx.x;
    if (i < n4) {
        float4 v = ((const float4*)in)[i];
        ushort4 o;
        o.x = f2bf(v.x); o.y = f2bf(v.y); o.z = f2bf(v.z); o.w = f2bf(v.w);
        ((ushort4*)out)[i] = o;
    }
}

// ---------------------------------------------------------------------------
// All 4 weight transposes (fp32 [2048][C] -> bf16 [C][2048]) in one dispatch;
// blockIdx.z selects the job. wq/wk/wv land stacked in wqkvT [3072][2048].
// ---------------------------------------------------------------------------
__global__ __launch_bounds__(256) void wtrans_kernel(
    const float* __restrict__ wq, const float* __restrict__ wk,
    const float* __restrict__ wv, const float* __restrict__ wo,
    u16* __restrict__ wqkvT, u16* __restrict__ woT)
{
    const int z = blockIdx.z;
    const float* src; u16* dst; int C;
    if (z == 0)      { src = wq; dst = wqkvT;                           C = 2048; }
    else if (z == 1) { src = wk; dst = wqkvT + (size_t)2048 * 2048;     C = 512;  }
    else if (z == 2) { src = wv; dst = wqkvT + (size_t)2560 * 2048;     C = 512;  }
    else             { src = wo; dst = woT;                             C = 2048; }
    const int c0 = blockIdx.x * 32;
    if (c0 >= C) return;
    const int r0 = blockIdx.y * 32;
    __shared__ float tile[32][33];
    const int tx = threadIdx.x & 31, ty = threadIdx.x >> 5;
#pragma unroll
    for (int i = 0; i < 32; i += 8)
        tile[ty + i][tx] = src[(size_t)(r0 + ty + i) * C + c0 + tx];
    __syncthreads();
#pragma unroll
    for (int i = 0; i < 32; i += 8)
        dst[(size_t)(c0 + ty + i) * 2048 + r0 + tx] = f2bf(tile[tx][ty + i]);
}

// ---------------------------------------------------------------------------
// Single-wave triple-buffered MFMA GEMM. Block = 64 threads = 1 wave owning a
// 64x64 C-tile (4x4 mfma_f32_16x16x32_bf16), BK=32.
//
// Pipeline DEPTH 2 (was 1): 3 LDS buffers, prefetch tile t+2 while computing
// tile t; s_waitcnt vmcnt(16) leaves tiles t+1,t+2 (16 DMAs) in flight.
// Rationale: grid gives only ~6 one-wave blocks/CU (1.5 waves/SIMD), so TLP
// can't cover the ~200-600cy L2/L3 load latency; depth-1 exposed most of it
// every iteration (MfmaUtil 11.6%). Depth-2 doubles issue->wait distance.
// 24KB LDS still fits 6 blocks/CU (144 < 160KB) -> occupancy unchanged.
//
// Buffer reuse safety (single wave, in-order issue): DMA of tile t+2 targets
// buf (t+2)%3 == buf (t-1)%3; tile t-1's ds_reads were register-consumed by
// MFMAs before iteration t's DMA instructions even issue.
//
// XCD swizzle: bijective remap (m204) so each of the 8 XCDs gets a contiguous
// chunk of the grid -> neighboring tiles share A-panels in that XCD's L2,
// cutting average load latency (we are latency-bound, not BW-bound).
//
// MODE 0: C fp32 [M][N].
// MODE 1: fused epilogue -> bf16 qkv [2048][3072]; cols<2560 get RoPE (pairs
//         are lane-adjacent: shfl_xor(v,1)); cols<2048 (Q) also scaled by
//         0.125*log2e so attention works in exp2 domain.
// ---------------------------------------------------------------------------
template <int MODE>
__global__ __launch_bounds__(64) void gemm1w_kernel(
    const u16* __restrict__ A, const u16* __restrict__ Bt, void* __restrict__ Cout,
    int N, int K, const float* __restrict__ fc, const float* __restrict__ fs)
{
    __shared__ __align__(16) u16 As[3][64 * 32];
    __shared__ __align__(16) u16 Bs[3][64 * 32];
    const int lane = threadIdx.x;

    // bijective XCD-aware block swizzle (8 XCDs)
    const int nwg = (int)(gridDim.x * gridDim.y);
    int bid = (int)blockIdx.y * (int)gridDim.x + (int)blockIdx.x;
    {
        const int q = nwg >> 3, r = nwg & 7;
        const int xcd = bid & 7, off = bid >> 3;
        bid = (xcd < r ? xcd * (q + 1) : r * (q + 1) + (xcd - r) * q) + off;
    }
    const int m0 = (bid / (int)gridDim.x) * 64, n0 = (bid % (int)gridDim.x) * 64;

    const int l15 = lane & 15, quad = lane >> 4, q8 = quad * 8;
    const int sr = lane >> 2, sc = (lane & 3) * 8;      // staging: 4 lanes/row

    const u16* pa = A  + (size_t)(m0 + sr) * K + sc;
    const u16* pb = Bt + (size_t)(n0 + sr) * K + sc;

    f32x4 acc[4][4];
#pragma unroll
    for (int i = 0; i < 4; ++i)
#pragma unroll
        for (int j = 0; j < 4; ++j) acc[i][j] = (f32x4){0.f, 0.f, 0.f, 0.f};

    const int nIter = K / 32;
    // prologue: tiles 0 and 1 into bufs 0,1
#pragma unroll
    for (int a = 0; a < 4; ++a) {
        gload_lds16(pa + a * 16 * K, &As[0][(a * 16 + sr) * 32 + sc]);
        gload_lds16(pb + a * 16 * K, &Bs[0][(a * 16 + sr) * 32 + sc]);
    }
#pragma unroll
    for (int a = 0; a < 4; ++a) {
        gload_lds16(pa + (size_t)a * 16 * K + 32, &As[1][(a * 16 + sr) * 32 + sc]);
        gload_lds16(pb + (size_t)a * 16 * K + 32, &Bs[1][(a * 16 + sr) * 32 + sc]);
    }
    int cb = 0, nb = 2;                                  // compute buf, prefetch buf
    for (int it = 0; it < nIter; ++it) {
        const int tp = it + 2;
        const int ktn = (tp < nIter) ? tp * 32 : 0;      // wrap: dummy prefetch
#pragma unroll
        for (int a = 0; a < 4; ++a) {
            gload_lds16(pa + (size_t)a * 16 * K + ktn, &As[nb][(a * 16 + sr) * 32 + sc]);
            gload_lds16(pb + (size_t)a * 16 * K + ktn, &Bs[nb][(a * 16 + sr) * 32 + sc]);
        }
        asm volatile("s_waitcnt vmcnt(16)" ::: "memory");  // tile t's 8 DMAs done; t+1,t+2 in flight
        bf16x8 af[4], bfr[4];
#pragma unroll
        for (int t = 0; t < 4; ++t) {
            af[t]  = *(const bf16x8*)&As[cb][(t * 16 + l15) * 32 + q8];
            bfr[t] = *(const bf16x8*)&Bs[cb][(t * 16 + l15) * 32 + q8];
        }
#pragma unroll
        for (int i = 0; i < 4; ++i)
#pragma unroll
            for (int j = 0; j < 4; ++j)
                acc[i][j] = __builtin_amdgcn_mfma_f32_16x16x32_bf16(af[i], bfr[j], acc[i][j], 0, 0, 0);
        cb = (cb == 2) ? 0 : cb + 1;
        nb = (nb == 2) ? 0 : nb + 1;
    }

    if (MODE == 0) {
        float* C = (float*)Cout;
#pragma unroll
        for (int i = 0; i < 4; ++i)
#pragma unroll
            for (int j = 0; j < 4; ++j)
#pragma unroll
                for (int r = 0; r < 4; ++r)
                    C[(size_t)(m0 + i * 16 + quad * 4 + r) * N + n0 + j * 16 + l15] = acc[i][j][r];
    } else {
        u16* O = (u16*)Cout;
        const bool do_rope = (n0 < 2560);                 // q & k regions
        const float scl = (n0 < 2048) ? QSCALE : 1.0f;    // q only
        const int odd = l15 & 1;
#pragma unroll
        for (int i = 0; i < 4; ++i)
#pragma unroll
            for (int j = 0; j < 4; ++j)
#pragma unroll
                for (int r = 0; r < 4; ++r) {
                    const int row = m0 + i * 16 + quad * 4 + r;
                    const int col = n0 + j * 16 + l15;
                    float v = acc[i][j][r], o;
                    if (do_rope) {
                        const int i2 = (j * 16 + l15) >> 1;   // head-dim pair (64-aligned tiles)
                        const float c = fc[row * 32 + i2], s = fs[row * 32 + i2];
                        const float p = __shfl_xor(v, 1);
                        o = (odd ? (p * s + v * c) : (v * c - p * s)) * scl;
                    } else {
                        o = v;                                // V: plain cast
                    }
                    O[(size_t)row * 3072 + col] = f2bf(o);
                }
    }
}

// ---------------------------------------------------------------------------
// V columns of qkv (bf16 [2048][3072], cols 2560..3071) -> vt bf16 [512][2048].
// ---------------------------------------------------------------------------
__global__ __launch_bounds__(256) void vtrans_kernel(
    const u16* __restrict__ qkv, u16* __restrict__ vt)
{
    __shared__ u16 tile[32][34];
    const int tx = threadIdx.x & 31, ty = threadIdx.x >> 5;
    const int r0 = blockIdx.y * 32, c0 = blockIdx.x * 32;
#pragma unroll
    for (int i = 0; i < 32; i += 8)
        tile[ty + i][tx] = qkv[(size_t)(r0 + ty + i) * 3072 + 2560 + c0 + tx];
    __syncthreads();
#pragma unroll
    for (int i = 0; i < 32; i += 8)
        vt[(size_t)(c0 + ty + i) * 2048 + r0 + tx] = tile[tx][ty + i];
}

// ---------------------------------------------------------------------------
// MFMA flash attention (causal, GQA), exp2 domain (Q pre-scaled by
// 0.125*log2e in the GEMM epilogue). Block = (head, 64 q-rows), 4 waves x 16
// rows. P repack C->A layout through per-wave bf16 LDS (16 b16 writes, 2
// conflict-free b128 reads). Row-sums via MFMA against a ones-fragment.
// ---------------------------------------------------------------------------
#define ATT_LDK 72     // u16 stride for K/V tiles (144B rows, 16B-aligned)
#define ATT_LDP 72     // u16 stride for P repack

__global__ __launch_bounds__(256) void attn_mfma_kernel(
    const u16* __restrict__ qkv,  // [2048][3072] bf16: q|k|v
    const u16* __restrict__ vt,   // [512][2048] bf16 (V^T)
    u16* __restrict__ ob)         // [2048][2048] bf16
{
    __shared__ __align__(16) u16 Ks[64 * ATT_LDK];
    __shared__ __align__(16) u16 Vs[64 * ATT_LDK];
    __shared__ __align__(16) u16 Ps[4][16 * ATT_LDP];

    const int h = blockIdx.x;
    const int tile = (int)gridDim.y - 1 - (int)blockIdx.y;  // big tiles first
    const int gkv = h >> 2;
    const int tid = threadIdx.x;
    const int w = tid >> 6, lane = tid & 63;
    const int l15 = lane & 15, quad = lane >> 4;
    const int q0 = tile * 64 + w * 16;

    bf16x8 ones;
#pragma unroll
    for (int j = 0; j < 8; ++j) ones[j] = (short)0x3F80;   // bf16 1.0

    bf16x8 qa[2];
    {
        const u16* qrow = qkv + (size_t)(q0 + l15) * 3072 + h * HD + quad * 8;
        qa[0] = *(const bf16x8*)(qrow);
        qa[1] = *(const bf16x8*)(qrow + 32);
    }
    f32x4 O[4];
#pragma unroll
    for (int i = 0; i < 4; ++i) O[i] = (f32x4){0.f, 0.f, 0.f, 0.f};
    float m_run[4], l_run[4];
#pragma unroll
    for (int r = 0; r < 4; ++r) { m_run[r] = -1e30f; l_run[r] = 0.f; }

    for (int c = 0; c <= tile; ++c) {
        const int key0 = c * 64;
        __syncthreads();
#pragma unroll
        for (int i = 0; i < 2; ++i) {
            int slot = tid + 256 * i;               // 0..511: 64 rows x 8 chunks
            int r = slot >> 3, o8 = (slot & 7) * 8;
            *(uint4*)&Ks[r * ATT_LDK + o8] =
                *(const uint4*)&qkv[(size_t)(key0 + r) * 3072 + 2048 + gkv * HD + o8];
            *(uint4*)&Vs[r * ATT_LDK + o8] =
                *(const uint4*)&vt[(size_t)(gkv * HD + r) * 2048 + key0 + o8];
        }
        __syncthreads();

        // S = Q K^T (log2 domain)
        f32x4 S[4];
#pragma unroll
        for (int kt = 0; kt < 4; ++kt) {
            bf16x8 b0 = *(const bf16x8*)&Ks[(kt * 16 + l15) * ATT_LDK + quad * 8];
            bf16x8 b1 = *(const bf16x8*)&Ks[(kt * 16 + l15) * ATT_LDK + 32 + quad * 8];
            f32x4 s = (f32x4){0.f, 0.f, 0.f, 0.f};
            s = __builtin_amdgcn_mfma_f32_16x16x32_bf16(qa[0], b0, s, 0, 0, 0);
            s = __builtin_amdgcn_mfma_f32_16x16x32_bf16(qa[1], b1, s, 0, 0, 0);
            S[kt] = s;
        }
        if (c == tile) {   // diagonal chunk causal mask (local coords)
#pragma unroll
            for (int kt = 0; kt < 4; ++kt) {
                int keyl = kt * 16 + l15;
#pragma unroll
                for (int r = 0; r < 4; ++r)
                    if (keyl > w * 16 + quad * 4 + r) S[kt][r] = -1e30f;
            }
        }
        // online softmax: max over row (16 lanes), exp2, alpha
        float alpha[4];
#pragma unroll
        for (int r = 0; r < 4; ++r) {
            float mx = fmaxf(fmaxf(S[0][r], S[1][r]), fmaxf(S[2][r], S[3][r]));
#pragma unroll
            for (int off = 1; off < 16; off <<= 1) mx = fmaxf(mx, __shfl_xor(mx, off));
            float mn = fmaxf(m_run[r], mx);
            alpha[r] = exp2f(m_run[r] - mn);
            m_run[r] = mn;
#pragma unroll
            for (int kt = 0; kt < 4; ++kt) S[kt][r] = exp2f(S[kt][r] - mn);
        }
        // P repack: C-layout -> A-layout, bf16 in LDS (same-wave, lgkm only)
        u16* pw = Ps[w];
#pragma unroll
        for (int kt = 0; kt < 4; ++kt)
#pragma unroll
            for (int r = 0; r < 4; ++r)
                pw[(quad * 4 + r) * ATT_LDP + kt * 16 + l15] = f2bf(S[kt][r]);
        bf16x8 pa0 = *(const bf16x8*)&pw[l15 * ATT_LDP + quad * 8];
        bf16x8 pa1 = *(const bf16x8*)&pw[l15 * ATT_LDP + 32 + quad * 8];

        // row-sums via MFMA with ones-B (replicated across l15 like m/l)
        f32x4 rs = (f32x4){0.f, 0.f, 0.f, 0.f};
        rs = __builtin_amdgcn_mfma_f32_16x16x32_bf16(pa0, ones, rs, 0, 0, 0);
        rs = __builtin_amdgcn_mfma_f32_16x16x32_bf16(pa1, ones, rs, 0, 0, 0);
#pragma unroll
        for (int r = 0; r < 4; ++r) l_run[r] = l_run[r] * alpha[r] + rs[r];

        // O = O*alpha + P V
#pragma unroll
        for (int dt = 0; dt < 4; ++dt)
#pragma unroll
            for (int r = 0; r < 4; ++r) O[dt][r] *= alpha[r];
#pragma unroll
        for (int dt = 0; dt < 4; ++dt) {
            bf16x8 b0 = *(const bf16x8*)&Vs[(dt * 16 + l15) * ATT_LDK + quad * 8];
            bf16x8 b1 = *(const bf16x8*)&Vs[(dt * 16 + l15) * ATT_LDK + 32 + quad * 8];
            O[dt] = __builtin_amdgcn_mfma_f32_16x16x32_bf16(pa0, b0, O[dt], 0, 0, 0);
            O[dt] = __builtin_amdgcn_mfma_f32_16x16x32_bf16(pa1, b1, O[dt], 0, 0, 0);
        }
    }
#pragma unroll
    for (int r = 0; r < 4; ++r) {
        float inv = 1.0f / l_run[r];
        u16* orow = ob + (size_t)(q0 + quad * 4 + r) * 2048 + h * HD;
#pragma unroll
        for (int dt = 0; dt < 4; ++dt)
            orow[dt * 16 + l15] = f2bf(O[dt][r] * inv);
    }
}

// ---------------------------------------------------------------------------
extern "C" void kernel_launch(void* const* d_in, const int* in_sizes, int n_in,
                              void* d_out, int out_size, void* d_ws, size_t ws_size,
                              hipStream_t stream)
{
    const float* x  = (const float*)d_in[0];
    const float* wq = (const float*)d_in[1];
    const float* wk = (const float*)d_in[2];
    const float* wv = (const float*)d_in[3];
    const float* wo = (const float*)d_in[4];
    const float* fc = (const float*)d_in[5];
    const float* fs = (const float*)d_in[6];
    // d_in[7] = mask: unused (hard causal == -1e9 additive path in fp32)
    float* out = (float*)d_out;

    // Workspace 50 MB:
    // xb 8MB | wqkvT 12MB | woT 8MB | qkv_bf 12MB | vt 2MB | ab 8MB
    u16* xb     = (u16*)d_ws;
    u16* wqkvT  = xb     + (size_t)2048 * 2048;
    u16* woT    = wqkvT  + (size_t)3072 * 2048;
    u16* qkv_bf = woT    + (size_t)2048 * 2048;
    u16* vt     = qkv_bf + (size_t)2048 * 3072;
    u16* ab     = vt     + (size_t)512 * 2048;

    cast_x_kernel<<<4096, 256, 0, stream>>>(x, xb, (2048 * 2048) / 4);
    wtrans_kernel<<<dim3(64, 64, 4), 256, 0, stream>>>(wq, wk, wv, wo, wqkvT, woT);

    // QKV projection + fused RoPE/scale/bf16 epilogue: [2048][3072]
    gemm1w_kernel<1><<<dim3(3072 / 64, 2048 / 64), 64, 0, stream>>>(
        xb, wqkvT, qkv_bf, 3072, 2048, fc, fs);

    vtrans_kernel<<<dim3(16, 64), 256, 0, stream>>>(qkv_bf, vt);

    attn_mfma_kernel<<<dim3(NH, L / 64), 256, 0, stream>>>(qkv_bf, vt, ab);

    // out projection -> fp32 output
    gemm1w_kernel<0><<<dim3(2048 / 64, 2048 / 64), 64, 0, stream>>>(
        ab, woT, out, 2048, 2048, nullptr, nullptr);
}

// Round 2
// 307.819 us; speedup vs baseline: 1.0402x; 1.0047x over previous
//
#include <hip/hip_runtime.h>
#include <hip/hip_bf16.h>

#define L 2048
#define D 2048
#define NH 32
#define NKV 8
#define HD 64

typedef unsigned short u16;
typedef __attribute__((ext_vector_type(8))) short bf16x8;   // 8 bf16 in 4 VGPRs
typedef __attribute__((ext_vector_type(4))) float f32x4;

#define QSCALE 0.1803368801f   // 0.125 * log2(e): S comes out in log2 domain

__device__ __forceinline__ u16 f2bf(float x) {
    __hip_bfloat16 b = __float2bfloat16(x);
    return *reinterpret_cast<u16*>(&b);
}

// Async global->LDS, 16B per lane. HW semantics: wave-uniform base (first
// lane's ptr) + lane*16; our layouts are lane-order contiguous to match.
__device__ __forceinline__ void gload_lds16(const void* g, void* l) {
    __builtin_amdgcn_global_load_lds(
        (const __attribute__((address_space(1))) unsigned int*)g,
        (__attribute__((address_space(3))) unsigned int*)l, 16, 0, 0);
}

// ---------------------------------------------------------------------------
// x fp32 -> bf16, float4-vectorized.
// ---------------------------------------------------------------------------
__global__ void cast_x_kernel(const float* __restrict__ in, u16* __restrict__ out, int n4)
{
    int i = blockIdx.x * 256 + threadIdx.x;
    if (i < n4) {
        float4 v = ((const float4*)in)[i];
        ushort4 o;
        o.x = f2bf(v.x); o.y = f2bf(v.y); o.z = f2bf(v.z); o.w = f2bf(v.w);
        ((ushort4*)out)[i] = o;
    }
}

// ---------------------------------------------------------------------------
// All 4 weight transposes (fp32 [2048][C] -> bf16 [C][2048]) in one dispatch;
// blockIdx.z selects the job. wq/wk/wv land stacked in wqkvT [3072][2048].
// ---------------------------------------------------------------------------
__global__ __launch_bounds__(256) void wtrans_kernel(
    const float* __restrict__ wq, const float* __restrict__ wk,
    const float* __restrict__ wv, const float* __restrict__ wo,
    u16* __restrict__ wqkvT, u16* __restrict__ woT)
{
    const int z = blockIdx.z;
    const float* src; u16* dst; int C;
    if (z == 0)      { src = wq; dst = wqkvT;                           C = 2048; }
    else if (z == 1) { src = wk; dst = wqkvT + (size_t)2048 * 2048;     C = 512;  }
    else if (z == 2) { src = wv; dst = wqkvT + (size_t)2560 * 2048;     C = 512;  }
    else             { src = wo; dst = woT;                             C = 2048; }
    const int c0 = blockIdx.x * 32;
    if (c0 >= C) return;
    const int r0 = blockIdx.y * 32;
    __shared__ float tile[32][33];
    const int tx = threadIdx.x & 31, ty = threadIdx.x >> 5;
#pragma unroll
    for (int i = 0; i < 32; i += 8)
        tile[ty + i][tx] = src[(size_t)(r0 + ty + i) * C + c0 + tx];
    __syncthreads();
#pragma unroll
    for (int i = 0; i < 32; i += 8)
        dst[(size_t)(c0 + ty + i) * 2048 + r0 + tx] = f2bf(tile[tx][ty + i]);
}

// ---------------------------------------------------------------------------
// 4-wave 128x128 MFMA GEMM, counted-vmcnt pipeline (NO syncthreads drain).
//
// Why: the 64x64 1-wave version was cache-BW-bound: 16 FLOP per staged byte
// -> 10.2 TB/s of L2/L3->CU traffic at only 335 TF. 128x128 doubles
// arithmetic intensity (32 FLOP/B), halving cache traffic per FLOP.
//
// Structure: 4 waves, each owns a 64x64 quadrant (4x4 mfma_f32_16x16x32_bf16).
// BK=32. 4 LDS buffers (64KB), pipeline depth 3. Per K-step:
//   s_waitcnt vmcnt(8)   -- own tile-t DMAs done; t+1,t+2 still in flight
//   s_barrier            -- all waves' tile-t DMAs done => tile complete
//   issue tile t+3 DMAs  -- into buf (t+3)%4 == buf of iter t-1 reads; safe:
//                           every wave consumed those ds_reads (lgkmcnt
//                           enforced before its MFMAs) before reaching the
//                           barrier above.
//   ds_read buf t%4 + 16 MFMA
// vmcnt never drains to 0 in the loop (T4); one raw barrier per K-step.
//
// Staging: 16KB/tile, 256 threads x 4 chunks of 16B. Wave w covers rows
// [w*16, w*16+16) and [64+w*16, 64+w*16+16) of both A and B tiles; LDS dest
// is wave-uniform base + lane*16 (lane-order contiguous rows of 64B).
//
// MODE 0: C fp32 [M][N].
// MODE 1: fused epilogue -> bf16 qkv [2048][3072]; col regions (Q<2048,
//         K<2560, V) are 128-aligned so per-block/per-wave uniform.
// ---------------------------------------------------------------------------
template <int MODE>
__global__ __launch_bounds__(256) void gemm4w_kernel(
    const u16* __restrict__ A, const u16* __restrict__ Bt, void* __restrict__ Cout,
    int N, int K, const float* __restrict__ fc, const float* __restrict__ fs)
{
    __shared__ __align__(16) u16 As[4][128 * 32];
    __shared__ __align__(16) u16 Bs[4][128 * 32];
    const int tid = threadIdx.x;
    const int w = tid >> 6, lane = tid & 63;

    // bijective XCD-aware block swizzle (both grids have nwg % 8 == 0)
    const int nwg = (int)(gridDim.x * gridDim.y);
    int bid = (int)blockIdx.y * (int)gridDim.x + (int)blockIdx.x;
    bid = (bid & 7) * (nwg >> 3) + (bid >> 3);
    const int m0 = (bid / (int)gridDim.x) * 128, n0 = (bid % (int)gridDim.x) * 128;

    const int l15 = lane & 15, quad = lane >> 4, q8 = quad * 8;
    const int sr = lane >> 2, sc = (lane & 3) * 8;      // staging: 4 lanes/row
    const int wr = (w >> 1) * 64, wc = (w & 1) * 64;    // wave's C-quadrant

    // staging source pointers (wave w: rows w*16.. and 64+w*16..)
    const u16* pa0 = A  + (size_t)(m0 + w * 16 + sr) * K + sc;
    const u16* pa1 = A  + (size_t)(m0 + 64 + w * 16 + sr) * K + sc;
    const u16* pb0 = Bt + (size_t)(n0 + w * 16 + sr) * K + sc;
    const u16* pb1 = Bt + (size_t)(n0 + 64 + w * 16 + sr) * K + sc;

    f32x4 acc[4][4];
#pragma unroll
    for (int i = 0; i < 4; ++i)
#pragma unroll
        for (int j = 0; j < 4; ++j) acc[i][j] = (f32x4){0.f, 0.f, 0.f, 0.f};

    const int nIter = K / 32;
    // prologue: tiles 0,1,2 (12 own DMAs in flight)
#pragma unroll
    for (int t = 0; t < 3; ++t) {
        const int ko = t * 32;
        gload_lds16(pa0 + ko, &As[t][(w * 16) * 32]);
        gload_lds16(pa1 + ko, &As[t][(64 + w * 16) * 32]);
        gload_lds16(pb0 + ko, &Bs[t][(w * 16) * 32]);
        gload_lds16(pb1 + ko, &Bs[t][(64 + w * 16) * 32]);
    }
    for (int it = 0; it < nIter; ++it) {
        asm volatile("s_waitcnt vmcnt(8)" ::: "memory");   // own tile-t DMAs done
        __builtin_amdgcn_s_barrier();                      // tile t complete for all
        const int tp = it + 3;
        const int ko = (tp < nIter) ? tp * 32 : 0;         // wrap: dummy prefetch
        const int nb = tp & 3, cb = it & 3;
        gload_lds16(pa0 + ko, &As[nb][(w * 16) * 32]);
        gload_lds16(pa1 + ko, &As[nb][(64 + w * 16) * 32]);
        gload_lds16(pb0 + ko, &Bs[nb][(w * 16) * 32]);
        gload_lds16(pb1 + ko, &Bs[nb][(64 + w * 16) * 32]);
        bf16x8 af[4], bfr[4];
#pragma unroll
        for (int t = 0; t < 4; ++t) {
            af[t]  = *(const bf16x8*)&As[cb][(wr + t * 16 + l15) * 32 + q8];
            bfr[t] = *(const bf16x8*)&Bs[cb][(wc + t * 16 + l15) * 32 + q8];
        }
#pragma unroll
        for (int i = 0; i < 4; ++i)
#pragma unroll
            for (int j = 0; j < 4; ++j)
                acc[i][j] = __builtin_amdgcn_mfma_f32_16x16x32_bf16(af[i], bfr[j], acc[i][j], 0, 0, 0);
    }

    if (MODE == 0) {
        float* C = (float*)Cout;
#pragma unroll
        for (int i = 0; i < 4; ++i)
#pragma unroll
            for (int j = 0; j < 4; ++j)
#pragma unroll
                for (int r = 0; r < 4; ++r)
                    C[(size_t)(m0 + wr + i * 16 + quad * 4 + r) * N + n0 + wc + j * 16 + l15] = acc[i][j][r];
    } else {
        u16* O = (u16*)Cout;
        const bool do_rope = (n0 + wc < 2560);            // q & k regions
        const float scl = (n0 + wc < 2048) ? QSCALE : 1.0f;  // q only
        const int odd = l15 & 1;
#pragma unroll
        for (int i = 0; i < 4; ++i)
#pragma unroll
            for (int j = 0; j < 4; ++j)
#pragma unroll
                for (int r = 0; r < 4; ++r) {
                    const int row = m0 + wr + i * 16 + quad * 4 + r;
                    const int col = n0 + wc + j * 16 + l15;
                    float v = acc[i][j][r], o;
                    if (do_rope) {
                        const int i2 = (j * 16 + l15) >> 1;   // head-dim pair (wc is 64-aligned)
                        const float c = fc[row * 32 + i2], s = fs[row * 32 + i2];
                        const float p = __shfl_xor(v, 1);
                        o = (odd ? (p * s + v * c) : (v * c - p * s)) * scl;
                    } else {
                        o = v;                                // V: plain cast
                    }
                    O[(size_t)row * 3072 + col] = f2bf(o);
                }
    }
}

// ---------------------------------------------------------------------------
// V columns of qkv (bf16 [2048][3072], cols 2560..3071) -> vt bf16 [512][2048].
// ---------------------------------------------------------------------------
__global__ __launch_bounds__(256) void vtrans_kernel(
    const u16* __restrict__ qkv, u16* __restrict__ vt)
{
    __shared__ u16 tile[32][34];
    const int tx = threadIdx.x & 31, ty = threadIdx.x >> 5;
    const int r0 = blockIdx.y * 32, c0 = blockIdx.x * 32;
#pragma unroll
    for (int i = 0; i < 32; i += 8)
        tile[ty + i][tx] = qkv[(size_t)(r0 + ty + i) * 3072 + 2560 + c0 + tx];
    __syncthreads();
#pragma unroll
    for (int i = 0; i < 32; i += 8)
        vt[(size_t)(c0 + ty + i) * 2048 + r0 + tx] = tile[tx][ty + i];
}

// ---------------------------------------------------------------------------
// MFMA flash attention (causal, GQA), exp2 domain (Q pre-scaled by
// 0.125*log2e in the GEMM epilogue). Block = (head, 64 q-rows), 4 waves x 16
// rows. P repack C->A layout through per-wave bf16 LDS (16 b16 writes, 2
// conflict-free b128 reads). Row-sums via MFMA against a ones-fragment.
// ---------------------------------------------------------------------------
#define ATT_LDK 72     // u16 stride for K/V tiles (144B rows, 16B-aligned)
#define ATT_LDP 72     // u16 stride for P repack

__global__ __launch_bounds__(256) void attn_mfma_kernel(
    const u16* __restrict__ qkv,  // [2048][3072] bf16: q|k|v
    const u16* __restrict__ vt,   // [512][2048] bf16 (V^T)
    u16* __restrict__ ob)         // [2048][2048] bf16
{
    __shared__ __align__(16) u16 Ks[64 * ATT_LDK];
    __shared__ __align__(16) u16 Vs[64 * ATT_LDK];
    __shared__ __align__(16) u16 Ps[4][16 * ATT_LDP];

    const int h = blockIdx.x;
    const int tile = (int)gridDim.y - 1 - (int)blockIdx.y;  // big tiles first
    const int gkv = h >> 2;
    const int tid = threadIdx.x;
    const int w = tid >> 6, lane = tid & 63;
    const int l15 = lane & 15, quad = lane >> 4;
    const int q0 = tile * 64 + w * 16;

    bf16x8 ones;
#pragma unroll
    for (int j = 0; j < 8; ++j) ones[j] = (short)0x3F80;   // bf16 1.0

    bf16x8 qa[2];
    {
        const u16* qrow = qkv + (size_t)(q0 + l15) * 3072 + h * HD + quad * 8;
        qa[0] = *(const bf16x8*)(qrow);
        qa[1] = *(const bf16x8*)(qrow + 32);
    }
    f32x4 O[4];
#pragma unroll
    for (int i = 0; i < 4; ++i) O[i] = (f32x4){0.f, 0.f, 0.f, 0.f};
    float m_run[4], l_run[4];
#pragma unroll
    for (int r = 0; r < 4; ++r) { m_run[r] = -1e30f; l_run[r] = 0.f; }

    for (int c = 0; c <= tile; ++c) {
        const int key0 = c * 64;
        __syncthreads();
#pragma unroll
        for (int i = 0; i < 2; ++i) {
            int slot = tid + 256 * i;               // 0..511: 64 rows x 8 chunks
            int r = slot >> 3, o8 = (slot & 7) * 8;
            *(uint4*)&Ks[r * ATT_LDK + o8] =
                *(const uint4*)&qkv[(size_t)(key0 + r) * 3072 + 2048 + gkv * HD + o8];
            *(uint4*)&Vs[r * ATT_LDK + o8] =
                *(const uint4*)&vt[(size_t)(gkv * HD + r) * 2048 + key0 + o8];
        }
        __syncthreads();

        // S = Q K^T (log2 domain)
        f32x4 S[4];
#pragma unroll
        for (int kt = 0; kt < 4; ++kt) {
            bf16x8 b0 = *(const bf16x8*)&Ks[(kt * 16 + l15) * ATT_LDK + quad * 8];
            bf16x8 b1 = *(const bf16x8*)&Ks[(kt * 16 + l15) * ATT_LDK + 32 + quad * 8];
            f32x4 s = (f32x4){0.f, 0.f, 0.f, 0.f};
            s = __builtin_amdgcn_mfma_f32_16x16x32_bf16(qa[0], b0, s, 0, 0, 0);
            s = __builtin_amdgcn_mfma_f32_16x16x32_bf16(qa[1], b1, s, 0, 0, 0);
            S[kt] = s;
        }
        if (c == tile) {   // diagonal chunk causal mask (local coords)
#pragma unroll
            for (int kt = 0; kt < 4; ++kt) {
                int keyl = kt * 16 + l15;
#pragma unroll
                for (int r = 0; r < 4; ++r)
                    if (keyl > w * 16 + quad * 4 + r) S[kt][r] = -1e30f;
            }
        }
        // online softmax: max over row (16 lanes), exp2, alpha
        float alpha[4];
#pragma unroll
        for (int r = 0; r < 4; ++r) {
            float mx = fmaxf(fmaxf(S[0][r], S[1][r]), fmaxf(S[2][r], S[3][r]));
#pragma unroll
            for (int off = 1; off < 16; off <<= 1) mx = fmaxf(mx, __shfl_xor(mx, off));
            float mn = fmaxf(m_run[r], mx);
            alpha[r] = exp2f(m_run[r] - mn);
            m_run[r] = mn;
#pragma unroll
            for (int kt = 0; kt < 4; ++kt) S[kt][r] = exp2f(S[kt][r] - mn);
        }
        // P repack: C-layout -> A-layout, bf16 in LDS (same-wave, lgkm only)
        u16* pw = Ps[w];
#pragma unroll
        for (int kt = 0; kt < 4; ++kt)
#pragma unroll
            for (int r = 0; r < 4; ++r)
                pw[(quad * 4 + r) * ATT_LDP + kt * 16 + l15] = f2bf(S[kt][r]);
        bf16x8 pa0 = *(const bf16x8*)&pw[l15 * ATT_LDP + quad * 8];
        bf16x8 pa1 = *(const bf16x8*)&pw[l15 * ATT_LDP + 32 + quad * 8];

        // row-sums via MFMA with ones-B (replicated across l15 like m/l)
        f32x4 rs = (f32x4){0.f, 0.f, 0.f, 0.f};
        rs = __builtin_amdgcn_mfma_f32_16x16x32_bf16(pa0, ones, rs, 0, 0, 0);
        rs = __builtin_amdgcn_mfma_f32_16x16x32_bf16(pa1, ones, rs, 0, 0, 0);
#pragma unroll
        for (int r = 0; r < 4; ++r) l_run[r] = l_run[r] * alpha[r] + rs[r];

        // O = O*alpha + P V
#pragma unroll
        for (int dt = 0; dt < 4; ++dt)
#pragma unroll
            for (int r = 0; r < 4; ++r) O[dt][r] *= alpha[r];
#pragma unroll
        for (int dt = 0; dt < 4; ++dt) {
            bf16x8 b0 = *(const bf16x8*)&Vs[(dt * 16 + l15) * ATT_LDK + quad * 8];
            bf16x8 b1 = *(const bf16x8*)&Vs[(dt * 16 + l15) * ATT_LDK + 32 + quad * 8];
            O[dt] = __builtin_amdgcn_mfma_f32_16x16x32_bf16(pa0, b0, O[dt], 0, 0, 0);
            O[dt] = __builtin_amdgcn_mfma_f32_16x16x32_bf16(pa1, b1, O[dt], 0, 0, 0);
        }
    }
#pragma unroll
    for (int r = 0; r < 4; ++r) {
        float inv = 1.0f / l_run[r];
        u16* orow = ob + (size_t)(q0 + quad * 4 + r) * 2048 + h * HD;
#pragma unroll
        for (int dt = 0; dt < 4; ++dt)
            orow[dt * 16 + l15] = f2bf(O[dt][r] * inv);
    }
}

// ---------------------------------------------------------------------------
extern "C" void kernel_launch(void* const* d_in, const int* in_sizes, int n_in,
                              void* d_out, int out_size, void* d_ws, size_t ws_size,
                              hipStream_t stream)
{
    const float* x  = (const float*)d_in[0];
    const float* wq = (const float*)d_in[1];
    const float* wk = (const float*)d_in[2];
    const float* wv = (const float*)d_in[3];
    const float* wo = (const float*)d_in[4];
    const float* fc = (const float*)d_in[5];
    const float* fs = (const float*)d_in[6];
    // d_in[7] = mask: unused (hard causal == -1e9 additive path in fp32)
    float* out = (float*)d_out;

    // Workspace 50 MB:
    // xb 8MB | wqkvT 12MB | woT 8MB | qkv_bf 12MB | vt 2MB | ab 8MB
    u16* xb     = (u16*)d_ws;
    u16* wqkvT  = xb     + (size_t)2048 * 2048;
    u16* woT    = wqkvT  + (size_t)3072 * 2048;
    u16* qkv_bf = woT    + (size_t)2048 * 2048;
    u16* vt     = qkv_bf + (size_t)2048 * 3072;
    u16* ab     = vt     + (size_t)512 * 2048;

    cast_x_kernel<<<4096, 256, 0, stream>>>(x, xb, (2048 * 2048) / 4);
    wtrans_kernel<<<dim3(64, 64, 4), 256, 0, stream>>>(wq, wk, wv, wo, wqkvT, woT);

    // QKV projection + fused RoPE/scale/bf16 epilogue: [2048][3072]
    gemm4w_kernel<1><<<dim3(3072 / 128, 2048 / 128), 256, 0, stream>>>(
        xb, wqkvT, qkv_bf, 3072, 2048, fc, fs);

    vtrans_kernel<<<dim3(16, 64), 256, 0, stream>>>(qkv_bf, vt);

    attn_mfma_kernel<<<dim3(NH, L / 64), 256, 0, stream>>>(qkv_bf, vt, ab);

    // out projection -> fp32 output
    gemm4w_kernel<0><<<dim3(2048 / 128, 2048 / 128), 256, 0, stream>>>(
        ab, woT, out, 2048, 2048, nullptr, nullptr);
}

// Round 3
// 299.886 us; speedup vs baseline: 1.0677x; 1.0265x over previous
//
#include <hip/hip_runtime.h>
#include <hip/hip_bf16.h>

#define L 2048
#define D 2048
#define NH 32
#define NKV 8
#define HD 64

typedef unsigned short u16;
typedef __attribute__((ext_vector_type(8))) short bf16x8;   // 8 bf16 in 4 VGPRs
typedef __attribute__((ext_vector_type(4))) float f32x4;

#define QSCALE 0.1803368801f   // 0.125 * log2(e): S comes out in log2 domain

__device__ __forceinline__ u16 f2bf(float x) {
    __hip_bfloat16 b = __float2bfloat16(x);
    return *reinterpret_cast<u16*>(&b);
}

// Async global->LDS, 16B per lane. HW semantics: wave-uniform base (first
// lane's ptr) + lane*16; our layouts are lane-order contiguous to match.
__device__ __forceinline__ void gload_lds16(const void* g, void* l) {
    __builtin_amdgcn_global_load_lds(
        (const __attribute__((address_space(1))) unsigned int*)g,
        (__attribute__((address_space(3))) unsigned int*)l, 16, 0, 0);
}

// ---------------------------------------------------------------------------
// Fused prep: z=0..3 weight transposes (fp32 [2048][C] -> bf16 [C][2048]),
// z=4: x fp32->bf16 cast. One dispatch instead of two (launch overhead ~10us
// per kernel in this harness).
// ---------------------------------------------------------------------------
__global__ __launch_bounds__(256) void prep_kernel(
    const float* __restrict__ x, u16* __restrict__ xb,
    const float* __restrict__ wq, const float* __restrict__ wk,
    const float* __restrict__ wv, const float* __restrict__ wo,
    u16* __restrict__ wqkvT, u16* __restrict__ woT)
{
    const int z = blockIdx.z;
    if (z == 4) {                                  // cast x: 4096 blocks cover 1M float4
        int i = (blockIdx.y * 64 + blockIdx.x) * 256 + threadIdx.x;
        float4 v = ((const float4*)x)[i];
        ushort4 o;
        o.x = f2bf(v.x); o.y = f2bf(v.y); o.z = f2bf(v.z); o.w = f2bf(v.w);
        ((ushort4*)xb)[i] = o;
        return;
    }
    const float* src; u16* dst; int C;
    if (z == 0)      { src = wq; dst = wqkvT;                           C = 2048; }
    else if (z == 1) { src = wk; dst = wqkvT + (size_t)2048 * 2048;     C = 512;  }
    else if (z == 2) { src = wv; dst = wqkvT + (size_t)2560 * 2048;     C = 512;  }
    else             { src = wo; dst = woT;                             C = 2048; }
    const int c0 = blockIdx.x * 32;
    if (c0 >= C) return;
    const int r0 = blockIdx.y * 32;
    __shared__ float tile[32][33];
    const int tx = threadIdx.x & 31, ty = threadIdx.x >> 5;
#pragma unroll
    for (int i = 0; i < 32; i += 8)
        tile[ty + i][tx] = src[(size_t)(r0 + ty + i) * C + c0 + tx];
    __syncthreads();
#pragma unroll
    for (int i = 0; i < 32; i += 8)
        dst[(size_t)(c0 + ty + i) * 2048 + r0 + tx] = f2bf(tile[tx][ty + i]);
}

// ---------------------------------------------------------------------------
// 4-wave 128x128 MFMA GEMM, TWO 32-K sub-tiles per wait-period.
//
// Empirical law from r0-r2: wall = nPeriods x ~2900cyc, nearly independent of
// tile size, DMA volume, prefetch depth, and blocks/CU (QKV and out-proj took
// identical time despite 1.5x FLOP difference). So: halve the period count.
// Each outer iteration consumes 64 K-columns (two 16KB sub-tile buffers) in
// one wait-period. 4 bufs (64KB) unchanged -> still 2 blocks/CU.
//
// Period structure (per-wave DMAs: 4 per sub-tile, 8 in flight):
//   s_waitcnt vmcnt(8)   -- subs 2t,2t+1 complete (2t+2,2t+3 in flight)
//   s_barrier            -- all waves' DMAs for these subs complete
//   ds_read both bufs (16 x b128)
//   s_waitcnt lgkmcnt(0) -- reads landed in regs
//   s_barrier            -- ALL waves consumed bufs cb0,cb1 => safe to overwrite
//   issue subs 2t+4 -> cb0, 2t+5 -> cb1 (8 DMAs)
//   32 MFMA
// Barriers via asm with memory clobber so no memory op crosses them.
//
// MODE 1: fused epilogue; Q/K cols get RoPE (+QSCALE for Q) -> qkv rows;
//         V cols are transposed through per-wave LDS scratch -> vt directly
//         (replaces the old vtrans kernel).
// MODE 0: C fp32 [M][N].
// ---------------------------------------------------------------------------
#define VT_LDS 72   // u16 stride for V-transpose scratch (144B, 16B-aligned)

template <int MODE>
__global__ __launch_bounds__(256) void gemm4w_kernel(
    const u16* __restrict__ A, const u16* __restrict__ Bt, void* __restrict__ Cout,
    int N, int K, const float* __restrict__ fc, const float* __restrict__ fs,
    u16* __restrict__ vt)
{
    __shared__ __align__(16) u16 As[4][128 * 32];
    __shared__ __align__(16) u16 Bs[4][128 * 32];
    const int tid = threadIdx.x;
    const int w = tid >> 6, lane = tid & 63;

    // bijective XCD-aware block swizzle (both grids have nwg % 8 == 0)
    const int nwg = (int)(gridDim.x * gridDim.y);
    int bid = (int)blockIdx.y * (int)gridDim.x + (int)blockIdx.x;
    bid = (bid & 7) * (nwg >> 3) + (bid >> 3);
    const int m0 = (bid / (int)gridDim.x) * 128, n0 = (bid % (int)gridDim.x) * 128;

    const int l15 = lane & 15, quad = lane >> 4, q8 = quad * 8;
    const int sr = lane >> 2, sc = (lane & 3) * 8;      // staging: 4 lanes/row
    const int wr = (w >> 1) * 64, wc = (w & 1) * 64;    // wave's C-quadrant

    // staging source pointers (wave w: rows w*16.. and 64+w*16..)
    const u16* pa0 = A  + (size_t)(m0 + w * 16 + sr) * K + sc;
    const u16* pa1 = A  + (size_t)(m0 + 64 + w * 16 + sr) * K + sc;
    const u16* pb0 = Bt + (size_t)(n0 + w * 16 + sr) * K + sc;
    const u16* pb1 = Bt + (size_t)(n0 + 64 + w * 16 + sr) * K + sc;

    f32x4 acc[4][4];
#pragma unroll
    for (int i = 0; i < 4; ++i)
#pragma unroll
        for (int j = 0; j < 4; ++j) acc[i][j] = (f32x4){0.f, 0.f, 0.f, 0.f};

    const int nSub = K / 32;          // 32-K sub-tiles
    const int nOut = nSub / 2;        // wait-periods
    // prologue: subs 0..3 into bufs 0..3, oldest-first
#pragma unroll
    for (int s = 0; s < 4; ++s) {
        const int ko = s * 32;
        gload_lds16(pa0 + ko, &As[s][(w * 16) * 32]);
        gload_lds16(pa1 + ko, &As[s][(64 + w * 16) * 32]);
        gload_lds16(pb0 + ko, &Bs[s][(w * 16) * 32]);
        gload_lds16(pb1 + ko, &Bs[s][(64 + w * 16) * 32]);
    }
    for (int it = 0; it < nOut; ++it) {
        const int s0 = 2 * it, cb0 = s0 & 3, cb1 = (s0 + 1) & 3;
        asm volatile("s_waitcnt vmcnt(8)" ::: "memory");   // subs s0,s0+1 done
        asm volatile("s_barrier" ::: "memory");            // ..for all waves
        bf16x8 a0[4], a1[4], b0[4], b1[4];
#pragma unroll
        for (int t = 0; t < 4; ++t) {
            a0[t] = *(const bf16x8*)&As[cb0][(wr + t * 16 + l15) * 32 + q8];
            b0[t] = *(const bf16x8*)&Bs[cb0][(wc + t * 16 + l15) * 32 + q8];
            a1[t] = *(const bf16x8*)&As[cb1][(wr + t * 16 + l15) * 32 + q8];
            b1[t] = *(const bf16x8*)&Bs[cb1][(wc + t * 16 + l15) * 32 + q8];
        }
        asm volatile("s_waitcnt lgkmcnt(0)" ::: "memory"); // reads in regs
        asm volatile("s_barrier" ::: "memory");            // all waves consumed bufs
        {
            const int sp0 = s0 + 4, sp1 = s0 + 5;
            const int k0 = (sp0 < nSub) ? sp0 * 32 : 0;    // wrap: dummy prefetch
            const int k1 = (sp1 < nSub) ? sp1 * 32 : 0;
            gload_lds16(pa0 + k0, &As[cb0][(w * 16) * 32]);
            gload_lds16(pa1 + k0, &As[cb0][(64 + w * 16) * 32]);
            gload_lds16(pb0 + k0, &Bs[cb0][(w * 16) * 32]);
            gload_lds16(pb1 + k0, &Bs[cb0][(64 + w * 16) * 32]);
            gload_lds16(pa0 + k1, &As[cb1][(w * 16) * 32]);
            gload_lds16(pa1 + k1, &As[cb1][(64 + w * 16) * 32]);
            gload_lds16(pb0 + k1, &Bs[cb1][(w * 16) * 32]);
            gload_lds16(pb1 + k1, &Bs[cb1][(64 + w * 16) * 32]);
        }
#pragma unroll
        for (int i = 0; i < 4; ++i)
#pragma unroll
            for (int j = 0; j < 4; ++j) {
                acc[i][j] = __builtin_amdgcn_mfma_f32_16x16x32_bf16(a0[i], b0[j], acc[i][j], 0, 0, 0);
                acc[i][j] = __builtin_amdgcn_mfma_f32_16x16x32_bf16(a1[i], b1[j], acc[i][j], 0, 0, 0);
            }
    }

    if (MODE == 0) {
        float* C = (float*)Cout;
#pragma unroll
        for (int i = 0; i < 4; ++i)
#pragma unroll
            for (int j = 0; j < 4; ++j)
#pragma unroll
                for (int r = 0; r < 4; ++r)
                    C[(size_t)(m0 + wr + i * 16 + quad * 4 + r) * N + n0 + wc + j * 16 + l15] = acc[i][j][r];
    } else {
        __syncthreads();                       // loop done everywhere; LDS reusable
        u16* O = (u16*)Cout;
        const int vc0 = n0 + wc;               // wave's first output column
        if (vc0 < 2560) {                      // Q or K region: RoPE + row store
            const float scl = (vc0 < 2048) ? QSCALE : 1.0f;   // q only
            const int odd = l15 & 1;
#pragma unroll
            for (int i = 0; i < 4; ++i)
#pragma unroll
                for (int j = 0; j < 4; ++j)
#pragma unroll
                    for (int r = 0; r < 4; ++r) {
                        const int row = m0 + wr + i * 16 + quad * 4 + r;
                        const int col = vc0 + j * 16 + l15;
                        float v = acc[i][j][r];
                        const int i2 = (j * 16 + l15) >> 1;   // head-dim pair (vc0 is 64-aligned)
                        const float c = fc[row * 32 + i2], s = fs[row * 32 + i2];
                        const float p = __shfl_xor(v, 1);
                        float o = (odd ? (p * s + v * c) : (v * c - p * s)) * scl;
                        O[(size_t)row * 3072 + col] = f2bf(o);
                    }
        } else {                               // V region: transpose -> vt via LDS
            u16* ws_ = (w < 2 ? (u16*)As : (u16*)Bs) + (w & 1) * (64 * VT_LDS);
#pragma unroll
            for (int i = 0; i < 4; ++i)
#pragma unroll
                for (int j = 0; j < 4; ++j)
#pragma unroll
                    for (int r = 0; r < 4; ++r)
                        ws_[(j * 16 + l15) * VT_LDS + i * 16 + quad * 4 + r] = f2bf(acc[i][j][r]);
            // ws_ is [64 vcols][64 seq]; read rows coalesced, write vt rows
#pragma unroll
            for (int t = 0; t < 8; ++t) {
                const int vr = t * 8 + (lane >> 3);
                const int c8 = (lane & 7) * 8;
                bf16x8 vv = *(const bf16x8*)&ws_[vr * VT_LDS + c8];
                *(bf16x8*)&vt[(size_t)(vc0 - 2560 + vr) * 2048 + m0 + wr + c8] = vv;
            }
        }
    }
}

// ---------------------------------------------------------------------------
// MFMA flash attention (causal, GQA), exp2 domain (Q pre-scaled by
// 0.125*log2e in the GEMM epilogue). Block = (head, 64 q-rows), 4 waves x 16
// rows. T14 async-STAGE: K/V tile c+1 is loaded into registers during tile
// c's compute and written to LDS after the next barrier, hiding the HBM/L2
// latency that previously sat serially between the two __syncthreads.
// ---------------------------------------------------------------------------
#define ATT_LDK 72     // u16 stride for K/V tiles (144B rows, 16B-aligned)
#define ATT_LDP 72     // u16 stride for P repack

__global__ __launch_bounds__(256) void attn_mfma_kernel(
    const u16* __restrict__ qkv,  // [2048][3072] bf16: q|k|v
    const u16* __restrict__ vt,   // [512][2048] bf16 (V^T)
    u16* __restrict__ ob)         // [2048][2048] bf16
{
    __shared__ __align__(16) u16 Ks[64 * ATT_LDK];
    __shared__ __align__(16) u16 Vs[64 * ATT_LDK];
    __shared__ __align__(16) u16 Ps[4][16 * ATT_LDP];

    const int h = blockIdx.x;
    const int tile = (int)gridDim.y - 1 - (int)blockIdx.y;  // big tiles first
    const int gkv = h >> 2;
    const int tid = threadIdx.x;
    const int w = tid >> 6, lane = tid & 63;
    const int l15 = lane & 15, quad = lane >> 4;
    const int q0 = tile * 64 + w * 16;

    bf16x8 ones;
#pragma unroll
    for (int j = 0; j < 8; ++j) ones[j] = (short)0x3F80;   // bf16 1.0

    bf16x8 qa[2];
    {
        const u16* qrow = qkv + (size_t)(q0 + l15) * 3072 + h * HD + quad * 8;
        qa[0] = *(const bf16x8*)(qrow);
        qa[1] = *(const bf16x8*)(qrow + 32);
    }
    f32x4 O[4];
#pragma unroll
    for (int i = 0; i < 4; ++i) O[i] = (f32x4){0.f, 0.f, 0.f, 0.f};
    float m_run[4], l_run[4];
#pragma unroll
    for (int r = 0; r < 4; ++r) { m_run[r] = -1e30f; l_run[r] = 0.f; }

    const int sslot = tid, sr0 = sslot >> 3, so8 = (sslot & 7) * 8;
    const int sslot1 = tid + 256, sr1 = sslot1 >> 3, so81 = (sslot1 & 7) * 8;

    uint4 kreg[2], vreg[2];
    kreg[0] = *(const uint4*)&qkv[(size_t)(sr0) * 3072 + 2048 + gkv * HD + so8];
    vreg[0] = *(const uint4*)&vt[(size_t)(gkv * HD + sr0) * 2048 + so8];
    kreg[1] = *(const uint4*)&qkv[(size_t)(sr1) * 3072 + 2048 + gkv * HD + so81];
    vreg[1] = *(const uint4*)&vt[(size_t)(gkv * HD + sr1) * 2048 + so81];

    for (int c = 0; c <= tile; ++c) {
        __syncthreads();                 // all readers of previous tile done
        *(uint4*)&Ks[sr0 * ATT_LDK + so8]  = kreg[0];
        *(uint4*)&Vs[sr0 * ATT_LDK + so8]  = vreg[0];
        *(uint4*)&Ks[sr1 * ATT_LDK + so81] = kreg[1];
        *(uint4*)&Vs[sr1 * ATT_LDK + so81] = vreg[1];
        __syncthreads();
        if (c < tile) {                  // prefetch next tile into regs
            const int kn = (c + 1) * 64;
            kreg[0] = *(const uint4*)&qkv[(size_t)(kn + sr0) * 3072 + 2048 + gkv * HD + so8];
            vreg[0] = *(const uint4*)&vt[(size_t)(gkv * HD + sr0) * 2048 + kn + so8];
            kreg[1] = *(const uint4*)&qkv[(size_t)(kn + sr1) * 3072 + 2048 + gkv * HD + so81];
            vreg[1] = *(const uint4*)&vt[(size_t)(gkv * HD + sr1) * 2048 + kn + so81];
        }

        // S = Q K^T (log2 domain)
        f32x4 S[4];
        __builtin_amdgcn_s_setprio(1);
#pragma unroll
        for (int kt = 0; kt < 4; ++kt) {
            bf16x8 b0 = *(const bf16x8*)&Ks[(kt * 16 + l15) * ATT_LDK + quad * 8];
            bf16x8 b1 = *(const bf16x8*)&Ks[(kt * 16 + l15) * ATT_LDK + 32 + quad * 8];
            f32x4 s = (f32x4){0.f, 0.f, 0.f, 0.f};
            s = __builtin_amdgcn_mfma_f32_16x16x32_bf16(qa[0], b0, s, 0, 0, 0);
            s = __builtin_amdgcn_mfma_f32_16x16x32_bf16(qa[1], b1, s, 0, 0, 0);
            S[kt] = s;
        }
        __builtin_amdgcn_s_setprio(0);
        if (c == tile) {   // diagonal chunk causal mask (local coords)
#pragma unroll
            for (int kt = 0; kt < 4; ++kt) {
                int keyl = kt * 16 + l15;
#pragma unroll
                for (int r = 0; r < 4; ++r)
                    if (keyl > w * 16 + quad * 4 + r) S[kt][r] = -1e30f;
            }
        }
        // online softmax: max over row (16 lanes), exp2, alpha
        float alpha[4];
#pragma unroll
        for (int r = 0; r < 4; ++r) {
            float mx = fmaxf(fmaxf(S[0][r], S[1][r]), fmaxf(S[2][r], S[3][r]));
#pragma unroll
            for (int off = 1; off < 16; off <<= 1) mx = fmaxf(mx, __shfl_xor(mx, off));
            float mn = fmaxf(m_run[r], mx);
            alpha[r] = exp2f(m_run[r] - mn);
            m_run[r] = mn;
#pragma unroll
            for (int kt = 0; kt < 4; ++kt) S[kt][r] = exp2f(S[kt][r] - mn);
        }
        // P repack: C-layout -> A-layout, bf16 in LDS (same-wave, lgkm only)
        u16* pw = Ps[w];
#pragma unroll
        for (int kt = 0; kt < 4; ++kt)
#pragma unroll
            for (int r = 0; r < 4; ++r)
                pw[(quad * 4 + r) * ATT_LDP + kt * 16 + l15] = f2bf(S[kt][r]);
        bf16x8 pa0 = *(const bf16x8*)&pw[l15 * ATT_LDP + quad * 8];
        bf16x8 pa1 = *(const bf16x8*)&pw[l15 * ATT_LDP + 32 + quad * 8];

        // row-sums via MFMA with ones-B (replicated across l15 like m/l)
        f32x4 rs = (f32x4){0.f, 0.f, 0.f, 0.f};
        rs = __builtin_amdgcn_mfma_f32_16x16x32_bf16(pa0, ones, rs, 0, 0, 0);
        rs = __builtin_amdgcn_mfma_f32_16x16x32_bf16(pa1, ones, rs, 0, 0, 0);
#pragma unroll
        for (int r = 0; r < 4; ++r) l_run[r] = l_run[r] * alpha[r] + rs[r];

        // O = O*alpha + P V
#pragma unroll
        for (int dt = 0; dt < 4; ++dt)
#pragma unroll
            for (int r = 0; r < 4; ++r) O[dt][r] *= alpha[r];
        __builtin_amdgcn_s_setprio(1);
#pragma unroll
        for (int dt = 0; dt < 4; ++dt) {
            bf16x8 b0 = *(const bf16x8*)&Vs[(dt * 16 + l15) * ATT_LDK + quad * 8];
            bf16x8 b1 = *(const bf16x8*)&Vs[(dt * 16 + l15) * ATT_LDK + 32 + quad * 8];
            O[dt] = __builtin_amdgcn_mfma_f32_16x16x32_bf16(pa0, b0, O[dt], 0, 0, 0);
            O[dt] = __builtin_amdgcn_mfma_f32_16x16x32_bf16(pa1, b1, O[dt], 0, 0, 0);
        }
        __builtin_amdgcn_s_setprio(0);
    }
#pragma unroll
    for (int r = 0; r < 4; ++r) {
        float inv = 1.0f / l_run[r];
        u16* orow = ob + (size_t)(q0 + quad * 4 + r) * 2048 + h * HD;
#pragma unroll
        for (int dt = 0; dt < 4; ++dt)
            orow[dt * 16 + l15] = f2bf(O[dt][r] * inv);
    }
}

// ---------------------------------------------------------------------------
extern "C" void kernel_launch(void* const* d_in, const int* in_sizes, int n_in,
                              void* d_out, int out_size, void* d_ws, size_t ws_size,
                              hipStream_t stream)
{
    const float* x  = (const float*)d_in[0];
    const float* wq = (const float*)d_in[1];
    const float* wk = (const float*)d_in[2];
    const float* wv = (const float*)d_in[3];
    const float* wo = (const float*)d_in[4];
    const float* fc = (const float*)d_in[5];
    const float* fs = (const float*)d_in[6];
    // d_in[7] = mask: unused (hard causal == -1e9 additive path in fp32)
    float* out = (float*)d_out;

    // Workspace 50 MB:
    // xb 8MB | wqkvT 12MB | woT 8MB | qkv_bf 12MB | vt 2MB | ab 8MB
    u16* xb     = (u16*)d_ws;
    u16* wqkvT  = xb     + (size_t)2048 * 2048;
    u16* woT    = wqkvT  + (size_t)3072 * 2048;
    u16* qkv_bf = woT    + (size_t)2048 * 2048;
    u16* vt     = qkv_bf + (size_t)2048 * 3072;
    u16* ab     = vt     + (size_t)512 * 2048;

    // prep: 4 weight transposes + x cast in one dispatch
    prep_kernel<<<dim3(64, 64, 5), 256, 0, stream>>>(x, xb, wq, wk, wv, wo, wqkvT, woT);

    // QKV projection + fused RoPE/scale/bf16 epilogue + V-transpose -> vt
    gemm4w_kernel<1><<<dim3(3072 / 128, 2048 / 128), 256, 0, stream>>>(
        xb, wqkvT, qkv_bf, 3072, 2048, fc, fs, vt);

    attn_mfma_kernel<<<dim3(NH, L / 64), 256, 0, stream>>>(qkv_bf, vt, ab);

    // out projection -> fp32 output
    gemm4w_kernel<0><<<dim3(2048 / 128, 2048 / 128), 256, 0, stream>>>(
        ab, woT, out, 2048, 2048, nullptr, nullptr, nullptr);
}

// Round 4
// 277.989 us; speedup vs baseline: 1.1518x; 1.0788x over previous
//
#include <hip/hip_runtime.h>
#include <hip/hip_bf16.h>

#define L 2048
#define D 2048
#define NH 32
#define NKV 8
#define HD 64

typedef unsigned short u16;
typedef __attribute__((ext_vector_type(8))) short bf16x8;   // 8 bf16 in 4 VGPRs
typedef __attribute__((ext_vector_type(4))) float f32x4;

#define QSCALE 0.1803368801f   // 0.125 * log2(e): S comes out in log2 domain

// Panel layout for GEMM operands: [dim0/128][k/32][128][32] (u16), so one
// 128x32 sub-tile = 8KB contiguous. off(d0,k) for K=2048:
//   ((d0>>7)*64 + (k>>5))*4096 + (d0&127)*32 + (k&31)
#define PANEL_OFF(d0, k) ((((size_t)((d0) >> 7) * 64 + ((k) >> 5)) << 12) + (((d0) & 127) << 5) + ((k) & 31))

__device__ __forceinline__ u16 f2bf(float x) {
    __hip_bfloat16 b = __float2bfloat16(x);
    return *reinterpret_cast<u16*>(&b);
}

// Async global->LDS, 16B per lane. Global src address is PER-LANE; LDS dest
// is wave-uniform base + lane*16.
__device__ __forceinline__ void gload_lds16(const void* g, void* l) {
    __builtin_amdgcn_global_load_lds(
        (const __attribute__((address_space(1))) unsigned int*)g,
        (__attribute__((address_space(3))) unsigned int*)l, 16, 0, 0);
}

// ---------------------------------------------------------------------------
// Fused prep: z=0..3 weight transposes fp32 [2048][C] -> bf16 PANEL layout;
// z=4: x fp32->bf16 cast into PANEL layout.
// ---------------------------------------------------------------------------
__global__ __launch_bounds__(256) void prep_kernel(
    const float* __restrict__ x, u16* __restrict__ xb,
    const float* __restrict__ wq, const float* __restrict__ wk,
    const float* __restrict__ wv, const float* __restrict__ wo,
    u16* __restrict__ wqkvT, u16* __restrict__ woT)
{
    const int z = blockIdx.z;
    if (z == 4) {                                  // cast x -> panels
        int i = (blockIdx.y * 64 + blockIdx.x) * 256 + threadIdx.x;  // float4 idx
        int e = i * 4;
        int row = e >> 11, k0 = e & 2047;          // x is [2048][2048]
        float4 v = ((const float4*)x)[i];
        ushort4 o;
        o.x = f2bf(v.x); o.y = f2bf(v.y); o.z = f2bf(v.z); o.w = f2bf(v.w);
        *(ushort4*)&xb[PANEL_OFF(row, k0)] = o;    // 4 elems same 32-block, 8B aligned
        return;
    }
    const float* src; u16* dst; int C;
    if (z == 0)      { src = wq; dst = wqkvT;                           C = 2048; }
    else if (z == 1) { src = wk; dst = wqkvT + (size_t)2048 * 2048;     C = 512;  }
    else if (z == 2) { src = wv; dst = wqkvT + (size_t)2560 * 2048;     C = 512;  }
    else             { src = wo; dst = woT;                             C = 2048; }
    const int c0 = blockIdx.x * 32;
    if (c0 >= C) return;
    const int r0 = blockIdx.y * 32;
    __shared__ float tile[32][33];
    const int tx = threadIdx.x & 31, ty = threadIdx.x >> 5;
#pragma unroll
    for (int i = 0; i < 32; i += 8)
        tile[ty + i][tx] = src[(size_t)(r0 + ty + i) * C + c0 + tx];
    __syncthreads();
#pragma unroll
    for (int i = 0; i < 32; i += 8) {
        const int n = c0 + ty + i, k = r0 + tx;    // n = output row (weight col), k = contraction
        dst[PANEL_OFF(n, k)] = f2bf(tile[tx][ty + i]);
    }
}

// ---------------------------------------------------------------------------
// 4-wave 128x128 MFMA GEMM on PANEL-layout operands.
//
// r0-r3 established: wall = ~2850cyc per 16KB-staged iteration, invariant to
// tile size/depth/periods => staging throughput wall (~5.75 B/cyc/CU) on the
// global_load_lds path. Old staging gathered 16 discontiguous 64B segments
// per DMA; panel layout makes each DMA one contiguous 1KB stream (lane i
// reads base+16i), the pattern m97-class kernels run at ~22 B/cyc/CU.
//
// Period structure (2 sub-tiles of K=32 per period, 4 bufs, 8 DMAs/wave
// in flight, vmcnt never drained in-loop):
//   s_waitcnt vmcnt(8); s_barrier        -- subs 2t,2t+1 resident
//   ds_read both bufs; lgkmcnt(0); s_barrier  -- bufs consumed by all waves
//   issue subs 2t+4,2t+5 (8 contiguous-1KB DMAs)
//   32 MFMA
//
// MODE 1: fused epilogue: Q/K cols RoPE (+QSCALE for Q) -> qkv rows (plain
//         layout for attn); V cols transposed through LDS -> vt rows.
// MODE 0: C fp32 [M][N] plain.
// ---------------------------------------------------------------------------
#define VT_LDS 72   // u16 stride for V-transpose scratch (144B, 16B-aligned)

template <int MODE>
__global__ __launch_bounds__(256) void gemm4w_kernel(
    const u16* __restrict__ A, const u16* __restrict__ Bt, void* __restrict__ Cout,
    int N, int K, const float* __restrict__ fc, const float* __restrict__ fs,
    u16* __restrict__ vt)
{
    __shared__ __align__(16) u16 As[4][128 * 32];
    __shared__ __align__(16) u16 Bs[4][128 * 32];
    const int tid = threadIdx.x;
    const int w = tid >> 6, lane = tid & 63;

    // bijective XCD-aware block swizzle (both grids have nwg % 8 == 0)
    const int nwg = (int)(gridDim.x * gridDim.y);
    int bid = (int)blockIdx.y * (int)gridDim.x + (int)blockIdx.x;
    bid = (bid & 7) * (nwg >> 3) + (bid >> 3);
    const int m0 = (bid / (int)gridDim.x) * 128, n0 = (bid % (int)gridDim.x) * 128;

    const int l15 = lane & 15, quad = lane >> 4, q8 = quad * 8;
    const int wr = (w >> 1) * 64, wc = (w & 1) * 64;    // wave's C-quadrant
    const int l8 = lane * 8;                            // u16 offset of lane's 16B
    const int wch = w * 1024;                           // wave's 2KB chunk of 8KB sub-tile

    // panel bases: sub-tile s of this block's panels is 4096 u16 at s*4096
    const u16* pa = A  + ((size_t)(m0 >> 7) * (K / 32) << 12);
    const u16* pb = Bt + ((size_t)(n0 >> 7) * (K / 32) << 12);

    f32x4 acc[4][4];
#pragma unroll
    for (int i = 0; i < 4; ++i)
#pragma unroll
        for (int j = 0; j < 4; ++j) acc[i][j] = (f32x4){0.f, 0.f, 0.f, 0.f};

    const int nSub = K / 32;          // 32-K sub-tiles
    const int nOut = nSub / 2;        // wait-periods
    // prologue: subs 0..3 into bufs 0..3, oldest-first (16 DMAs in flight)
#pragma unroll
    for (int s = 0; s < 4; ++s) {
        const size_t so = (size_t)s << 12;
        gload_lds16(pa + so + wch + l8,       &As[s][wch]);
        gload_lds16(pa + so + wch + 512 + l8, &As[s][wch + 512]);
        gload_lds16(pb + so + wch + l8,       &Bs[s][wch]);
        gload_lds16(pb + so + wch + 512 + l8, &Bs[s][wch + 512]);
    }
    for (int it = 0; it < nOut; ++it) {
        const int s0 = 2 * it, cb0 = s0 & 3, cb1 = (s0 + 1) & 3;
        asm volatile("s_waitcnt vmcnt(8)" ::: "memory");   // subs s0,s0+1 done
        asm volatile("s_barrier" ::: "memory");            // ..for all waves
        bf16x8 a0[4], a1[4], b0[4], b1[4];
#pragma unroll
        for (int t = 0; t < 4; ++t) {
            a0[t] = *(const bf16x8*)&As[cb0][(wr + t * 16 + l15) * 32 + q8];
            b0[t] = *(const bf16x8*)&Bs[cb0][(wc + t * 16 + l15) * 32 + q8];
            a1[t] = *(const bf16x8*)&As[cb1][(wr + t * 16 + l15) * 32 + q8];
            b1[t] = *(const bf16x8*)&Bs[cb1][(wc + t * 16 + l15) * 32 + q8];
        }
        asm volatile("s_waitcnt lgkmcnt(0)" ::: "memory"); // reads in regs
        asm volatile("s_barrier" ::: "memory");            // all waves consumed bufs
        {
            const int sp0 = s0 + 4, sp1 = s0 + 5;
            const size_t k0 = (size_t)((sp0 < nSub) ? sp0 : 0) << 12;  // wrap: dummy
            const size_t k1 = (size_t)((sp1 < nSub) ? sp1 : 0) << 12;
            gload_lds16(pa + k0 + wch + l8,       &As[cb0][wch]);
            gload_lds16(pa + k0 + wch + 512 + l8, &As[cb0][wch + 512]);
            gload_lds16(pb + k0 + wch + l8,       &Bs[cb0][wch]);
            gload_lds16(pb + k0 + wch + 512 + l8, &Bs[cb0][wch + 512]);
            gload_lds16(pa + k1 + wch + l8,       &As[cb1][wch]);
            gload_lds16(pa + k1 + wch + 512 + l8, &As[cb1][wch + 512]);
            gload_lds16(pb + k1 + wch + l8,       &Bs[cb1][wch]);
            gload_lds16(pb + k1 + wch + 512 + l8, &Bs[cb1][wch + 512]);
        }
#pragma unroll
        for (int i = 0; i < 4; ++i)
#pragma unroll
            for (int j = 0; j < 4; ++j) {
                acc[i][j] = __builtin_amdgcn_mfma_f32_16x16x32_bf16(a0[i], b0[j], acc[i][j], 0, 0, 0);
                acc[i][j] = __builtin_amdgcn_mfma_f32_16x16x32_bf16(a1[i], b1[j], acc[i][j], 0, 0, 0);
            }
    }

    if (MODE == 0) {
        float* C = (float*)Cout;
#pragma unroll
        for (int i = 0; i < 4; ++i)
#pragma unroll
            for (int j = 0; j < 4; ++j)
#pragma unroll
                for (int r = 0; r < 4; ++r)
                    C[(size_t)(m0 + wr + i * 16 + quad * 4 + r) * N + n0 + wc + j * 16 + l15] = acc[i][j][r];
    } else {
        __syncthreads();                       // loop done everywhere; LDS reusable
        u16* O = (u16*)Cout;
        const int vc0 = n0 + wc;               // wave's first output column
        if (vc0 < 2560) {                      // Q or K region: RoPE + row store
            const float scl = (vc0 < 2048) ? QSCALE : 1.0f;   // q only
            const int odd = l15 & 1;
#pragma unroll
            for (int i = 0; i < 4; ++i)
#pragma unroll
                for (int j = 0; j < 4; ++j)
#pragma unroll
                    for (int r = 0; r < 4; ++r) {
                        const int row = m0 + wr + i * 16 + quad * 4 + r;
                        const int col = vc0 + j * 16 + l15;
                        float v = acc[i][j][r];
                        const int i2 = (j * 16 + l15) >> 1;   // head-dim pair (vc0 is 64-aligned)
                        const float c = fc[row * 32 + i2], s = fs[row * 32 + i2];
                        const float p = __shfl_xor(v, 1);
                        float o = (odd ? (p * s + v * c) : (v * c - p * s)) * scl;
                        O[(size_t)row * 3072 + col] = f2bf(o);
                    }
        } else {                               // V region: transpose -> vt via LDS
            u16* ws_ = (w < 2 ? (u16*)As : (u16*)Bs) + (w & 1) * (64 * VT_LDS);
#pragma unroll
            for (int i = 0; i < 4; ++i)
#pragma unroll
                for (int j = 0; j < 4; ++j)
#pragma unroll
                    for (int r = 0; r < 4; ++r)
                        ws_[(j * 16 + l15) * VT_LDS + i * 16 + quad * 4 + r] = f2bf(acc[i][j][r]);
            // ws_ is [64 vcols][64 seq]; read rows coalesced, write vt rows
#pragma unroll
            for (int t = 0; t < 8; ++t) {
                const int vr = t * 8 + (lane >> 3);
                const int c8 = (lane & 7) * 8;
                bf16x8 vv = *(const bf16x8*)&ws_[vr * VT_LDS + c8];
                *(bf16x8*)&vt[(size_t)(vc0 - 2560 + vr) * 2048 + m0 + wr + c8] = vv;
            }
        }
    }
}

// ---------------------------------------------------------------------------
// MFMA flash attention (causal, GQA), exp2 domain (Q pre-scaled by
// 0.125*log2e in the GEMM epilogue). Block = (head, 64 q-rows), 4 waves x 16
// rows. REVERTED to the r2 structure (inline staging): the r3 reg-prefetch
// pushed the allocator into scratch spills (VGPR 88->56, +75MB scratch
// writes, 77->112us). Only change vs r2: output goes to ab in PANEL layout
// (pure address change) for the out-projection's contiguous staging.
// ---------------------------------------------------------------------------
#define ATT_LDK 72     // u16 stride for K/V tiles (144B rows, 16B-aligned)
#define ATT_LDP 72     // u16 stride for P repack

__global__ __launch_bounds__(256) void attn_mfma_kernel(
    const u16* __restrict__ qkv,  // [2048][3072] bf16: q|k|v
    const u16* __restrict__ vt,   // [512][2048] bf16 (V^T)
    u16* __restrict__ ab)         // panel-layout bf16 [16][64][128][32]
{
    __shared__ __align__(16) u16 Ks[64 * ATT_LDK];
    __shared__ __align__(16) u16 Vs[64 * ATT_LDK];
    __shared__ __align__(16) u16 Ps[4][16 * ATT_LDP];

    const int h = blockIdx.x;
    const int tile = (int)gridDim.y - 1 - (int)blockIdx.y;  // big tiles first
    const int gkv = h >> 2;
    const int tid = threadIdx.x;
    const int w = tid >> 6, lane = tid & 63;
    const int l15 = lane & 15, quad = lane >> 4;
    const int q0 = tile * 64 + w * 16;

    bf16x8 ones;
#pragma unroll
    for (int j = 0; j < 8; ++j) ones[j] = (short)0x3F80;   // bf16 1.0

    bf16x8 qa[2];
    {
        const u16* qrow = qkv + (size_t)(q0 + l15) * 3072 + h * HD + quad * 8;
        qa[0] = *(const bf16x8*)(qrow);
        qa[1] = *(const bf16x8*)(qrow + 32);
    }
    f32x4 O[4];
#pragma unroll
    for (int i = 0; i < 4; ++i) O[i] = (f32x4){0.f, 0.f, 0.f, 0.f};
    float m_run[4], l_run[4];
#pragma unroll
    for (int r = 0; r < 4; ++r) { m_run[r] = -1e30f; l_run[r] = 0.f; }

    for (int c = 0; c <= tile; ++c) {
        const int key0 = c * 64;
        __syncthreads();
#pragma unroll
        for (int i = 0; i < 2; ++i) {
            int slot = tid + 256 * i;               // 0..511: 64 rows x 8 chunks
            int r = slot >> 3, o8 = (slot & 7) * 8;
            *(uint4*)&Ks[r * ATT_LDK + o8] =
                *(const uint4*)&qkv[(size_t)(key0 + r) * 3072 + 2048 + gkv * HD + o8];
            *(uint4*)&Vs[r * ATT_LDK + o8] =
                *(const uint4*)&vt[(size_t)(gkv * HD + r) * 2048 + key0 + o8];
        }
        __syncthreads();

        // S = Q K^T (log2 domain)
        f32x4 S[4];
#pragma unroll
        for (int kt = 0; kt < 4; ++kt) {
            bf16x8 b0 = *(const bf16x8*)&Ks[(kt * 16 + l15) * ATT_LDK + quad * 8];
            bf16x8 b1 = *(const bf16x8*)&Ks[(kt * 16 + l15) * ATT_LDK + 32 + quad * 8];
            f32x4 s = (f32x4){0.f, 0.f, 0.f, 0.f};
            s = __builtin_amdgcn_mfma_f32_16x16x32_bf16(qa[0], b0, s, 0, 0, 0);
            s = __builtin_amdgcn_mfma_f32_16x16x32_bf16(qa[1], b1, s, 0, 0, 0);
            S[kt] = s;
        }
        if (c == tile) {   // diagonal chunk causal mask (local coords)
#pragma unroll
            for (int kt = 0; kt < 4; ++kt) {
                int keyl = kt * 16 + l15;
#pragma unroll
                for (int r = 0; r < 4; ++r)
                    if (keyl > w * 16 + quad * 4 + r) S[kt][r] = -1e30f;
            }
        }
        // online softmax: max over row (16 lanes), exp2, alpha
        float alpha[4];
#pragma unroll
        for (int r = 0; r < 4; ++r) {
            float mx = fmaxf(fmaxf(S[0][r], S[1][r]), fmaxf(S[2][r], S[3][r]));
#pragma unroll
            for (int off = 1; off < 16; off <<= 1) mx = fmaxf(mx, __shfl_xor(mx, off));
            float mn = fmaxf(m_run[r], mx);
            alpha[r] = exp2f(m_run[r] - mn);
            m_run[r] = mn;
#pragma unroll
            for (int kt = 0; kt < 4; ++kt) S[kt][r] = exp2f(S[kt][r] - mn);
        }
        // P repack: C-layout -> A-layout, bf16 in LDS (same-wave, lgkm only)
        u16* pw = Ps[w];
#pragma unroll
        for (int kt = 0; kt < 4; ++kt)
#pragma unroll
            for (int r = 0; r < 4; ++r)
                pw[(quad * 4 + r) * ATT_LDP + kt * 16 + l15] = f2bf(S[kt][r]);
        bf16x8 pa0 = *(const bf16x8*)&pw[l15 * ATT_LDP + quad * 8];
        bf16x8 pa1 = *(const bf16x8*)&pw[l15 * ATT_LDP + 32 + quad * 8];

        // row-sums via MFMA with ones-B (replicated across l15 like m/l)
        f32x4 rs = (f32x4){0.f, 0.f, 0.f, 0.f};
        rs = __builtin_amdgcn_mfma_f32_16x16x32_bf16(pa0, ones, rs, 0, 0, 0);
        rs = __builtin_amdgcn_mfma_f32_16x16x32_bf16(pa1, ones, rs, 0, 0, 0);
#pragma unroll
        for (int r = 0; r < 4; ++r) l_run[r] = l_run[r] * alpha[r] + rs[r];

        // O = O*alpha + P V
#pragma unroll
        for (int dt = 0; dt < 4; ++dt)
#pragma unroll
            for (int r = 0; r < 4; ++r) O[dt][r] *= alpha[r];
#pragma unroll
        for (int dt = 0; dt < 4; ++dt) {
            bf16x8 b0 = *(const bf16x8*)&Vs[(dt * 16 + l15) * ATT_LDK + quad * 8];
            bf16x8 b1 = *(const bf16x8*)&Vs[(dt * 16 + l15) * ATT_LDK + 32 + quad * 8];
            O[dt] = __builtin_amdgcn_mfma_f32_16x16x32_bf16(pa0, b0, O[dt], 0, 0, 0);
            O[dt] = __builtin_amdgcn_mfma_f32_16x16x32_bf16(pa1, b1, O[dt], 0, 0, 0);
        }
    }
#pragma unroll
    for (int r = 0; r < 4; ++r) {
        float inv = 1.0f / l_run[r];
        const int q = q0 + quad * 4 + r;
#pragma unroll
        for (int dt = 0; dt < 4; ++dt) {
            const int col = h * HD + dt * 16 + l15;
            ab[PANEL_OFF(q, col)] = f2bf(O[dt][r] * inv);
        }
    }
}

// ---------------------------------------------------------------------------
extern "C" void kernel_launch(void* const* d_in, const int* in_sizes, int n_in,
                              void* d_out, int out_size, void* d_ws, size_t ws_size,
                              hipStream_t stream)
{
    const float* x  = (const float*)d_in[0];
    const float* wq = (const float*)d_in[1];
    const float* wk = (const float*)d_in[2];
    const float* wv = (const float*)d_in[3];
    const float* wo = (const float*)d_in[4];
    const float* fc = (const float*)d_in[5];
    const float* fs = (const float*)d_in[6];
    // d_in[7] = mask: unused (hard causal == -1e9 additive path in fp32)
    float* out = (float*)d_out;

    // Workspace 50 MB:
    // xb 8MB | wqkvT 12MB | woT 8MB | qkv_bf 12MB | vt 2MB | ab 8MB
    // xb, wqkvT, woT, ab are PANEL layout; qkv_bf, vt plain.
    u16* xb     = (u16*)d_ws;
    u16* wqkvT  = xb     + (size_t)2048 * 2048;
    u16* woT    = wqkvT  + (size_t)3072 * 2048;
    u16* qkv_bf = woT    + (size_t)2048 * 2048;
    u16* vt     = qkv_bf + (size_t)2048 * 3072;
    u16* ab     = vt     + (size_t)512 * 2048;

    // prep: 4 weight transposes + x cast in one dispatch (panel outputs)
    prep_kernel<<<dim3(64, 64, 5), 256, 0, stream>>>(x, xb, wq, wk, wv, wo, wqkvT, woT);

    // QKV projection + fused RoPE/scale/bf16 epilogue + V-transpose -> vt
    gemm4w_kernel<1><<<dim3(3072 / 128, 2048 / 128), 256, 0, stream>>>(
        xb, wqkvT, qkv_bf, 3072, 2048, fc, fs, vt);

    attn_mfma_kernel<<<dim3(NH, L / 64), 256, 0, stream>>>(qkv_bf, vt, ab);

    // out projection -> fp32 output
    gemm4w_kernel<0><<<dim3(2048 / 128, 2048 / 128), 256, 0, stream>>>(
        ab, woT, out, 2048, 2048, nullptr, nullptr, nullptr);
}

// Round 5
// 249.813 us; speedup vs baseline: 1.2818x; 1.1128x over previous
//
#include <hip/hip_runtime.h>
#include <hip/hip_bf16.h>

#define L 2048
#define D 2048
#define NH 32
#define NKV 8
#define HD 64

typedef unsigned short u16;
typedef __attribute__((ext_vector_type(8))) short bf16x8;   // 8 bf16 in 4 VGPRs
typedef __attribute__((ext_vector_type(4))) float f32x4;

#define QSCALE 0.1803368801f   // 0.125 * log2(e): S comes out in log2 domain

// Panel layout for GEMM operands: [dim0/128][k/32][128][32] (u16), so one
// 128x32 sub-tile = 8KB contiguous. off(d0,k) for K=2048:
//   ((d0>>7)*64 + (k>>5))*4096 + (d0&127)*32 + (k&31)
#define PANEL_OFF(d0, k) ((((size_t)((d0) >> 7) * 64 + ((k) >> 5)) << 12) + (((d0) & 127) << 5) + ((k) & 31))

__device__ __forceinline__ u16 f2bf(float x) {
    __hip_bfloat16 b = __float2bfloat16(x);
    return *reinterpret_cast<u16*>(&b);
}

// Async global->LDS, 16B per lane. Global src address is PER-LANE; LDS dest
// is wave-uniform base + lane*16.
__device__ __forceinline__ void gload_lds16(const void* g, void* l) {
    __builtin_amdgcn_global_load_lds(
        (const __attribute__((address_space(1))) unsigned int*)g,
        (__attribute__((address_space(3))) unsigned int*)l, 16, 0, 0);
}

// ---------------------------------------------------------------------------
// Fused prep: z=0..3 weight transposes fp32 [2048][C] -> bf16 PANEL layout;
// z=4: x fp32->bf16 cast into PANEL layout.
// ---------------------------------------------------------------------------
__global__ __launch_bounds__(256) void prep_kernel(
    const float* __restrict__ x, u16* __restrict__ xb,
    const float* __restrict__ wq, const float* __restrict__ wk,
    const float* __restrict__ wv, const float* __restrict__ wo,
    u16* __restrict__ wqkvT, u16* __restrict__ woT)
{
    const int z = blockIdx.z;
    if (z == 4) {                                  // cast x -> panels
        int i = (blockIdx.y * 64 + blockIdx.x) * 256 + threadIdx.x;  // float4 idx
        int e = i * 4;
        int row = e >> 11, k0 = e & 2047;          // x is [2048][2048]
        float4 v = ((const float4*)x)[i];
        ushort4 o;
        o.x = f2bf(v.x); o.y = f2bf(v.y); o.z = f2bf(v.z); o.w = f2bf(v.w);
        *(ushort4*)&xb[PANEL_OFF(row, k0)] = o;    // 4 elems same 32-block, 8B aligned
        return;
    }
    const float* src; u16* dst; int C;
    if (z == 0)      { src = wq; dst = wqkvT;                           C = 2048; }
    else if (z == 1) { src = wk; dst = wqkvT + (size_t)2048 * 2048;     C = 512;  }
    else if (z == 2) { src = wv; dst = wqkvT + (size_t)2560 * 2048;     C = 512;  }
    else             { src = wo; dst = woT;                             C = 2048; }
    const int c0 = blockIdx.x * 32;
    if (c0 >= C) return;
    const int r0 = blockIdx.y * 32;
    __shared__ float tile[32][33];
    const int tx = threadIdx.x & 31, ty = threadIdx.x >> 5;
#pragma unroll
    for (int i = 0; i < 32; i += 8)
        tile[ty + i][tx] = src[(size_t)(r0 + ty + i) * C + c0 + tx];
    __syncthreads();
#pragma unroll
    for (int i = 0; i < 32; i += 8) {
        const int n = c0 + ty + i, k = r0 + tx;    // n = output row (weight col), k = contraction
        dst[PANEL_OFF(n, k)] = f2bf(tile[tx][ty + i]);
    }
}

// ---------------------------------------------------------------------------
// 4-wave 128x128 MFMA GEMM on PANEL-layout operands. (unchanged from r4 --
// the panel layout fixed the staging-throughput wall.)
// ---------------------------------------------------------------------------
#define VT_LDS 72   // u16 stride for V-transpose scratch (144B, 16B-aligned)

template <int MODE>
__global__ __launch_bounds__(256) void gemm4w_kernel(
    const u16* __restrict__ A, const u16* __restrict__ Bt, void* __restrict__ Cout,
    int N, int K, const float* __restrict__ fc, const float* __restrict__ fs,
    u16* __restrict__ vt)
{
    __shared__ __align__(16) u16 As[4][128 * 32];
    __shared__ __align__(16) u16 Bs[4][128 * 32];
    const int tid = threadIdx.x;
    const int w = tid >> 6, lane = tid & 63;

    // bijective XCD-aware block swizzle (both grids have nwg % 8 == 0)
    const int nwg = (int)(gridDim.x * gridDim.y);
    int bid = (int)blockIdx.y * (int)gridDim.x + (int)blockIdx.x;
    bid = (bid & 7) * (nwg >> 3) + (bid >> 3);
    const int m0 = (bid / (int)gridDim.x) * 128, n0 = (bid % (int)gridDim.x) * 128;

    const int l15 = lane & 15, quad = lane >> 4, q8 = quad * 8;
    const int wr = (w >> 1) * 64, wc = (w & 1) * 64;    // wave's C-quadrant
    const int l8 = lane * 8;                            // u16 offset of lane's 16B
    const int wch = w * 1024;                           // wave's 2KB chunk of 8KB sub-tile

    // panel bases: sub-tile s of this block's panels is 4096 u16 at s*4096
    const u16* pa = A  + ((size_t)(m0 >> 7) * (K / 32) << 12);
    const u16* pb = Bt + ((size_t)(n0 >> 7) * (K / 32) << 12);

    f32x4 acc[4][4];
#pragma unroll
    for (int i = 0; i < 4; ++i)
#pragma unroll
        for (int j = 0; j < 4; ++j) acc[i][j] = (f32x4){0.f, 0.f, 0.f, 0.f};

    const int nSub = K / 32;          // 32-K sub-tiles
    const int nOut = nSub / 2;        // wait-periods
    // prologue: subs 0..3 into bufs 0..3, oldest-first (16 DMAs in flight)
#pragma unroll
    for (int s = 0; s < 4; ++s) {
        const size_t so = (size_t)s << 12;
        gload_lds16(pa + so + wch + l8,       &As[s][wch]);
        gload_lds16(pa + so + wch + 512 + l8, &As[s][wch + 512]);
        gload_lds16(pb + so + wch + l8,       &Bs[s][wch]);
        gload_lds16(pb + so + wch + 512 + l8, &Bs[s][wch + 512]);
    }
    for (int it = 0; it < nOut; ++it) {
        const int s0 = 2 * it, cb0 = s0 & 3, cb1 = (s0 + 1) & 3;
        asm volatile("s_waitcnt vmcnt(8)" ::: "memory");   // subs s0,s0+1 done
        asm volatile("s_barrier" ::: "memory");            // ..for all waves
        bf16x8 a0[4], a1[4], b0[4], b1[4];
#pragma unroll
        for (int t = 0; t < 4; ++t) {
            a0[t] = *(const bf16x8*)&As[cb0][(wr + t * 16 + l15) * 32 + q8];
            b0[t] = *(const bf16x8*)&Bs[cb0][(wc + t * 16 + l15) * 32 + q8];
            a1[t] = *(const bf16x8*)&As[cb1][(wr + t * 16 + l15) * 32 + q8];
            b1[t] = *(const bf16x8*)&Bs[cb1][(wc + t * 16 + l15) * 32 + q8];
        }
        asm volatile("s_waitcnt lgkmcnt(0)" ::: "memory"); // reads in regs
        asm volatile("s_barrier" ::: "memory");            // all waves consumed bufs
        {
            const int sp0 = s0 + 4, sp1 = s0 + 5;
            const size_t k0 = (size_t)((sp0 < nSub) ? sp0 : 0) << 12;  // wrap: dummy
            const size_t k1 = (size_t)((sp1 < nSub) ? sp1 : 0) << 12;
            gload_lds16(pa + k0 + wch + l8,       &As[cb0][wch]);
            gload_lds16(pa + k0 + wch + 512 + l8, &As[cb0][wch + 512]);
            gload_lds16(pb + k0 + wch + l8,       &Bs[cb0][wch]);
            gload_lds16(pb + k0 + wch + 512 + l8, &Bs[cb0][wch + 512]);
            gload_lds16(pa + k1 + wch + l8,       &As[cb1][wch]);
            gload_lds16(pa + k1 + wch + 512 + l8, &As[cb1][wch + 512]);
            gload_lds16(pb + k1 + wch + l8,       &Bs[cb1][wch]);
            gload_lds16(pb + k1 + wch + 512 + l8, &Bs[cb1][wch + 512]);
        }
#pragma unroll
        for (int i = 0; i < 4; ++i)
#pragma unroll
            for (int j = 0; j < 4; ++j) {
                acc[i][j] = __builtin_amdgcn_mfma_f32_16x16x32_bf16(a0[i], b0[j], acc[i][j], 0, 0, 0);
                acc[i][j] = __builtin_amdgcn_mfma_f32_16x16x32_bf16(a1[i], b1[j], acc[i][j], 0, 0, 0);
            }
    }

    if (MODE == 0) {
        float* C = (float*)Cout;
#pragma unroll
        for (int i = 0; i < 4; ++i)
#pragma unroll
            for (int j = 0; j < 4; ++j)
#pragma unroll
                for (int r = 0; r < 4; ++r)
                    C[(size_t)(m0 + wr + i * 16 + quad * 4 + r) * N + n0 + wc + j * 16 + l15] = acc[i][j][r];
    } else {
        __syncthreads();                       // loop done everywhere; LDS reusable
        u16* O = (u16*)Cout;
        const int vc0 = n0 + wc;               // wave's first output column
        if (vc0 < 2560) {                      // Q or K region: RoPE + row store
            const float scl = (vc0 < 2048) ? QSCALE : 1.0f;   // q only
            const int odd = l15 & 1;
#pragma unroll
            for (int i = 0; i < 4; ++i)
#pragma unroll
                for (int j = 0; j < 4; ++j)
#pragma unroll
                    for (int r = 0; r < 4; ++r) {
                        const int row = m0 + wr + i * 16 + quad * 4 + r;
                        const int col = vc0 + j * 16 + l15;
                        float v = acc[i][j][r];
                        const int i2 = (j * 16 + l15) >> 1;   // head-dim pair (vc0 is 64-aligned)
                        const float c = fc[row * 32 + i2], s = fs[row * 32 + i2];
                        const float p = __shfl_xor(v, 1);
                        float o = (odd ? (p * s + v * c) : (v * c - p * s)) * scl;
                        O[(size_t)row * 3072 + col] = f2bf(o);
                    }
        } else {                               // V region: transpose -> vt via LDS
            u16* ws_ = (w < 2 ? (u16*)As : (u16*)Bs) + (w & 1) * (64 * VT_LDS);
#pragma unroll
            for (int i = 0; i < 4; ++i)
#pragma unroll
                for (int j = 0; j < 4; ++j)
#pragma unroll
                    for (int r = 0; r < 4; ++r)
                        ws_[(j * 16 + l15) * VT_LDS + i * 16 + quad * 4 + r] = f2bf(acc[i][j][r]);
            // ws_ is [64 vcols][64 seq]; read rows coalesced, write vt rows
#pragma unroll
            for (int t = 0; t < 8; ++t) {
                const int vr = t * 8 + (lane >> 3);
                const int c8 = (lane & 7) * 8;
                bf16x8 vv = *(const bf16x8*)&ws_[vr * VT_LDS + c8];
                *(bf16x8*)&vt[(size_t)(vc0 - 2560 + vr) * 2048 + m0 + wr + c8] = vv;
            }
        }
    }
}

// ---------------------------------------------------------------------------
// MFMA flash attention (causal, GQA), exp2 domain. Block = (head, 64 q-rows),
// 4 waves x 16 rows.
//
// r5 staging rework: K/V staged via global_load_lds into DOUBLE-BUFFERED
// linear LDS tiles with counted vmcnt -- the latency that used to sit
// serially between two __syncthreads is now hidden under the previous tile's
// compute, with ZERO register pressure (r3's reg-prefetch spilled).
// Linear LDS rows are 128B => classic 32-way bank conflict on ds_read_b128;
// fixed by both-sides XOR swizzle (T2/m173): the per-lane GLOBAL source
// chunk is XOR'd by (row&7), the ds_read applies the same XOR, LDS stays
// linear as global_load_lds requires.
//
// Per tile c:  STAGE(c+1 -> buf^1)  [4 DMAs/wave, into buffer all waves
//              finished reading at the end of iter c-1]
//              s_waitcnt vmcnt(4)   [tile c's DMAs done; c+1's in flight]
//              s_barrier            [..for all waves]
//              compute tile c       [swizzled ds_reads, MFMA, softmax]
//              s_barrier            [all waves done reading buf c]
// ---------------------------------------------------------------------------
#define ATT_LDP 72     // u16 stride for P repack

__global__ __launch_bounds__(256) void attn_mfma_kernel(
    const u16* __restrict__ qkv,  // [2048][3072] bf16: q|k|v
    const u16* __restrict__ vt,   // [512][2048] bf16 (V^T)
    u16* __restrict__ ab)         // panel-layout bf16 [16][64][128][32]
{
    __shared__ __align__(16) u16 Ks[2][64 * 64];   // linear, swizzled content
    __shared__ __align__(16) u16 Vs[2][64 * 64];
    __shared__ __align__(16) u16 Ps[4][16 * ATT_LDP];

    const int h = blockIdx.x;
    const int tile = (int)gridDim.y - 1 - (int)blockIdx.y;  // big tiles first
    const int gkv = h >> 2;
    const int tid = threadIdx.x;
    const int w = tid >> 6, lane = tid & 63;
    const int l15 = lane & 15, quad = lane >> 4;
    const int q0 = tile * 64 + w * 16;

    // staging geometry: wave w stages rows [w*16, w*16+16) of K and of V
    // (2 instrs of 8 rows each). lane covers row r0+(lane>>3), chunk lane&7;
    // global source chunk is XOR-swizzled by (row&7).
    const int srow = lane >> 3, schunk = lane & 7;
    const int r0_ = w * 16 + srow, r1_ = w * 16 + 8 + srow;
    const int c0_ = (schunk ^ (r0_ & 7)) * 8, c1_ = (schunk ^ (r1_ & 7)) * 8;
    const u16* kbase = qkv + 2048 + gkv * HD;      // + (key0+row)*3072 + chunk
    const u16* vbase = vt + (size_t)gkv * HD * 2048;  // + row*2048 + key0 + chunk

    bf16x8 ones;
#pragma unroll
    for (int j = 0; j < 8; ++j) ones[j] = (short)0x3F80;   // bf16 1.0

    bf16x8 qa[2];
    {
        const u16* qrow = qkv + (size_t)(q0 + l15) * 3072 + h * HD + quad * 8;
        qa[0] = *(const bf16x8*)(qrow);
        qa[1] = *(const bf16x8*)(qrow + 32);
    }
    f32x4 O[4];
#pragma unroll
    for (int i = 0; i < 4; ++i) O[i] = (f32x4){0.f, 0.f, 0.f, 0.f};
    float m_run[4], l_run[4];
#pragma unroll
    for (int r = 0; r < 4; ++r) { m_run[r] = -1e30f; l_run[r] = 0.f; }

    // prologue: tile 0 into buf 0 (4 DMAs/wave)
    gload_lds16(kbase + (size_t)r0_ * 3072 + c0_,        &Ks[0][(w * 16) * 64]);
    gload_lds16(kbase + (size_t)r1_ * 3072 + c1_,        &Ks[0][(w * 16 + 8) * 64]);
    gload_lds16(vbase + (size_t)r0_ * 2048 + c0_,        &Vs[0][(w * 16) * 64]);
    gload_lds16(vbase + (size_t)r1_ * 2048 + c1_,        &Vs[0][(w * 16 + 8) * 64]);

    for (int c = 0; c <= tile; ++c) {
        const int cb = c & 1, nb = cb ^ 1;
        const int kn = (c < tile ? c + 1 : tile) * 64;   // clamp: dummy re-stage
        gload_lds16(kbase + (size_t)(kn + r0_) * 3072 + c0_, &Ks[nb][(w * 16) * 64]);
        gload_lds16(kbase + (size_t)(kn + r1_) * 3072 + c1_, &Ks[nb][(w * 16 + 8) * 64]);
        gload_lds16(vbase + (size_t)r0_ * 2048 + kn + c0_,   &Vs[nb][(w * 16) * 64]);
        gload_lds16(vbase + (size_t)r1_ * 2048 + kn + c1_,   &Vs[nb][(w * 16 + 8) * 64]);
        asm volatile("s_waitcnt vmcnt(4)" ::: "memory");   // tile c's 4 done
        asm volatile("s_barrier" ::: "memory");            // ..for all waves

        // S = Q K^T (log2 domain), swizzled K reads
        f32x4 S[4];
        __builtin_amdgcn_s_setprio(1);
#pragma unroll
        for (int kt = 0; kt < 4; ++kt) {
            const int kr = kt * 16 + l15, kx = (kr & 7);
            bf16x8 b0 = *(const bf16x8*)&Ks[cb][kr * 64 + ((quad ^ kx) * 8)];
            bf16x8 b1 = *(const bf16x8*)&Ks[cb][kr * 64 + (((quad + 4) ^ kx) * 8)];
            f32x4 s = (f32x4){0.f, 0.f, 0.f, 0.f};
            s = __builtin_amdgcn_mfma_f32_16x16x32_bf16(qa[0], b0, s, 0, 0, 0);
            s = __builtin_amdgcn_mfma_f32_16x16x32_bf16(qa[1], b1, s, 0, 0, 0);
            S[kt] = s;
        }
        __builtin_amdgcn_s_setprio(0);
        if (c == tile) {   // diagonal chunk causal mask (local coords)
#pragma unroll
            for (int kt = 0; kt < 4; ++kt) {
                int keyl = kt * 16 + l15;
#pragma unroll
                for (int r = 0; r < 4; ++r)
                    if (keyl > w * 16 + quad * 4 + r) S[kt][r] = -1e30f;
            }
        }
        // online softmax: max over row (16 lanes), exp2, alpha
        float alpha[4];
#pragma unroll
        for (int r = 0; r < 4; ++r) {
            float mx = fmaxf(fmaxf(S[0][r], S[1][r]), fmaxf(S[2][r], S[3][r]));
#pragma unroll
            for (int off = 1; off < 16; off <<= 1) mx = fmaxf(mx, __shfl_xor(mx, off));
            float mn = fmaxf(m_run[r], mx);
            alpha[r] = exp2f(m_run[r] - mn);
            m_run[r] = mn;
#pragma unroll
            for (int kt = 0; kt < 4; ++kt) S[kt][r] = exp2f(S[kt][r] - mn);
        }
        // P repack: C-layout -> A-layout, bf16 in LDS (same-wave, lgkm only)
        u16* pw = Ps[w];
#pragma unroll
        for (int kt = 0; kt < 4; ++kt)
#pragma unroll
            for (int r = 0; r < 4; ++r)
                pw[(quad * 4 + r) * ATT_LDP + kt * 16 + l15] = f2bf(S[kt][r]);
        bf16x8 pa0 = *(const bf16x8*)&pw[l15 * ATT_LDP + quad * 8];
        bf16x8 pa1 = *(const bf16x8*)&pw[l15 * ATT_LDP + 32 + quad * 8];

        // row-sums via MFMA with ones-B (replicated across l15 like m/l)
        f32x4 rs = (f32x4){0.f, 0.f, 0.f, 0.f};
        rs = __builtin_amdgcn_mfma_f32_16x16x32_bf16(pa0, ones, rs, 0, 0, 0);
        rs = __builtin_amdgcn_mfma_f32_16x16x32_bf16(pa1, ones, rs, 0, 0, 0);
#pragma unroll
        for (int r = 0; r < 4; ++r) l_run[r] = l_run[r] * alpha[r] + rs[r];

        // O = O*alpha + P V   (swizzled V reads)
#pragma unroll
        for (int dt = 0; dt < 4; ++dt)
#pragma unroll
            for (int r = 0; r < 4; ++r) O[dt][r] *= alpha[r];
        __builtin_amdgcn_s_setprio(1);
#pragma unroll
        for (int dt = 0; dt < 4; ++dt) {
            const int vr = dt * 16 + l15, vx = (vr & 7);
            bf16x8 b0 = *(const bf16x8*)&Vs[cb][vr * 64 + ((quad ^ vx) * 8)];
            bf16x8 b1 = *(const bf16x8*)&Vs[cb][vr * 64 + (((quad + 4) ^ vx) * 8)];
            O[dt] = __builtin_amdgcn_mfma_f32_16x16x32_bf16(pa0, b0, O[dt], 0, 0, 0);
            O[dt] = __builtin_amdgcn_mfma_f32_16x16x32_bf16(pa1, b1, O[dt], 0, 0, 0);
        }
        __builtin_amdgcn_s_setprio(0);
        asm volatile("s_barrier" ::: "memory");            // all waves done reading buf cb
    }
#pragma unroll
    for (int r = 0; r < 4; ++r) {
        float inv = 1.0f / l_run[r];
        const int q = q0 + quad * 4 + r;
        const int pbase = ((q >> 7) << 18) + ((q & 127) << 5);   // 32-bit panel math
#pragma unroll
        for (int dt = 0; dt < 4; ++dt) {
            const int col = h * HD + dt * 16 + l15;
            ab[pbase + ((col >> 5) << 12) + (col & 31)] = f2bf(O[dt][r] * inv);
        }
    }
}

// ---------------------------------------------------------------------------
extern "C" void kernel_launch(void* const* d_in, const int* in_sizes, int n_in,
                              void* d_out, int out_size, void* d_ws, size_t ws_size,
                              hipStream_t stream)
{
    const float* x  = (const float*)d_in[0];
    const float* wq = (const float*)d_in[1];
    const float* wk = (const float*)d_in[2];
    const float* wv = (const float*)d_in[3];
    const float* wo = (const float*)d_in[4];
    const float* fc = (const float*)d_in[5];
    const float* fs = (const float*)d_in[6];
    // d_in[7] = mask: unused (hard causal == -1e9 additive path in fp32)
    float* out = (float*)d_out;

    // Workspace 50 MB:
    // xb 8MB | wqkvT 12MB | woT 8MB | qkv_bf 12MB | vt 2MB | ab 8MB
    // xb, wqkvT, woT, ab are PANEL layout; qkv_bf, vt plain.
    u16* xb     = (u16*)d_ws;
    u16* wqkvT  = xb     + (size_t)2048 * 2048;
    u16* woT    = wqkvT  + (size_t)3072 * 2048;
    u16* qkv_bf = woT    + (size_t)2048 * 2048;
    u16* vt     = qkv_bf + (size_t)2048 * 3072;
    u16* ab     = vt     + (size_t)512 * 2048;

    // prep: 4 weight transposes + x cast in one dispatch (panel outputs)
    prep_kernel<<<dim3(64, 64, 5), 256, 0, stream>>>(x, xb, wq, wk, wv, wo, wqkvT, woT);

    // QKV projection + fused RoPE/scale/bf16 epilogue + V-transpose -> vt
    gemm4w_kernel<1><<<dim3(3072 / 128, 2048 / 128), 256, 0, stream>>>(
        xb, wqkvT, qkv_bf, 3072, 2048, fc, fs, vt);

    attn_mfma_kernel<<<dim3(NH, L / 64), 256, 0, stream>>>(qkv_bf, vt, ab);

    // out projection -> fp32 output
    gemm4w_kernel<0><<<dim3(2048 / 128, 2048 / 128), 256, 0, stream>>>(
        ab, woT, out, 2048, 2048, nullptr, nullptr, nullptr);
}

// Round 8
// 245.296 us; speedup vs baseline: 1.3054x; 1.0184x over previous
//
#include <hip/hip_runtime.h>
#include <hip/hip_bf16.h>

#define L 2048
#define D 2048
#define NH 32
#define NKV 8
#define HD 64

typedef unsigned short u16;
typedef __attribute__((ext_vector_type(8))) short bf16x8;   // 8 bf16 in 4 VGPRs
typedef __attribute__((ext_vector_type(4))) short bf16x4;   // 4 bf16 in 2 VGPRs
typedef __attribute__((ext_vector_type(4))) float f32x4;

#define QSCALE 0.1803368801f   // 0.125 * log2(e): S comes out in log2 domain

// 16x16x16 bf16 MFMA (K=16): the _1k builtin, called DIRECTLY.
// - no __has_builtin guard: it returns false for aux-target builtins in the
//   HIP host pass (r6 failure), while direct calls parse fine in both passes
//   (proven by our 16x16x32 usage).
// - no inline asm: r7's asm version produced NaN; INLINEASM producers are
//   opaque to the GCN hazard recognizer, so MFMA->VALU wait states may be
//   dropped -> undefined D-register reads. The builtin restores
//   compiler-managed MAI hazard handling.
__device__ __forceinline__ f32x4 mfma16(bf16x4 a, bf16x4 b, f32x4 c) {
    return __builtin_amdgcn_mfma_f32_16x16x16bf16_1k(a, b, c, 0, 0, 0);
}

// Panel layout for GEMM operands: [dim0/128][k/32][128][32] (u16), so one
// 128x32 sub-tile = 8KB contiguous. off(d0,k) for K=2048:
//   ((d0>>7)*64 + (k>>5))*4096 + (d0&127)*32 + (k&31)
#define PANEL_OFF(d0, k) ((((size_t)((d0) >> 7) * 64 + ((k) >> 5)) << 12) + (((d0) & 127) << 5) + ((k) & 31))

__device__ __forceinline__ u16 f2bf(float x) {
    __hip_bfloat16 b = __float2bfloat16(x);
    return *reinterpret_cast<u16*>(&b);
}

// Async global->LDS, 16B per lane. Global src address is PER-LANE; LDS dest
// is wave-uniform base + lane*16.
__device__ __forceinline__ void gload_lds16(const void* g, void* l) {
    __builtin_amdgcn_global_load_lds(
        (const __attribute__((address_space(1))) unsigned int*)g,
        (__attribute__((address_space(3))) unsigned int*)l, 16, 0, 0);
}

// ---------------------------------------------------------------------------
// Fused prep: z=0..3 weight transposes fp32 [2048][C] -> bf16 PANEL layout;
// z=4: x fp32->bf16 cast into PANEL layout.  (unchanged from r4/r5)
// ---------------------------------------------------------------------------
__global__ __launch_bounds__(256) void prep_kernel(
    const float* __restrict__ x, u16* __restrict__ xb,
    const float* __restrict__ wq, const float* __restrict__ wk,
    const float* __restrict__ wv, const float* __restrict__ wo,
    u16* __restrict__ wqkvT, u16* __restrict__ woT)
{
    const int z = blockIdx.z;
    if (z == 4) {                                  // cast x -> panels
        int i = (blockIdx.y * 64 + blockIdx.x) * 256 + threadIdx.x;  // float4 idx
        int e = i * 4;
        int row = e >> 11, k0 = e & 2047;          // x is [2048][2048]
        float4 v = ((const float4*)x)[i];
        ushort4 o;
        o.x = f2bf(v.x); o.y = f2bf(v.y); o.z = f2bf(v.z); o.w = f2bf(v.w);
        *(ushort4*)&xb[PANEL_OFF(row, k0)] = o;    // 4 elems same 32-block, 8B aligned
        return;
    }
    const float* src; u16* dst; int C;
    if (z == 0)      { src = wq; dst = wqkvT;                           C = 2048; }
    else if (z == 1) { src = wk; dst = wqkvT + (size_t)2048 * 2048;     C = 512;  }
    else if (z == 2) { src = wv; dst = wqkvT + (size_t)2560 * 2048;     C = 512;  }
    else             { src = wo; dst = woT;                             C = 2048; }
    const int c0 = blockIdx.x * 32;
    if (c0 >= C) return;
    const int r0 = blockIdx.y * 32;
    __shared__ float tile[32][33];
    const int tx = threadIdx.x & 31, ty = threadIdx.x >> 5;
#pragma unroll
    for (int i = 0; i < 32; i += 8)
        tile[ty + i][tx] = src[(size_t)(r0 + ty + i) * C + c0 + tx];
    __syncthreads();
#pragma unroll
    for (int i = 0; i < 32; i += 8) {
        const int n = c0 + ty + i, k = r0 + tx;    // n = output row (weight col), k = contraction
        dst[PANEL_OFF(n, k)] = f2bf(tile[tx][ty + i]);
    }
}

// ---------------------------------------------------------------------------
// 4-wave 128x128 MFMA GEMM on PANEL-layout operands. (unchanged from r4/r5)
// ---------------------------------------------------------------------------
#define VT_LDS 72   // u16 stride for V-transpose scratch (144B, 16B-aligned)

template <int MODE>
__global__ __launch_bounds__(256) void gemm4w_kernel(
    const u16* __restrict__ A, const u16* __restrict__ Bt, void* __restrict__ Cout,
    int N, int K, const float* __restrict__ fc, const float* __restrict__ fs,
    u16* __restrict__ vt)
{
    __shared__ __align__(16) u16 As[4][128 * 32];
    __shared__ __align__(16) u16 Bs[4][128 * 32];
    const int tid = threadIdx.x;
    const int w = tid >> 6, lane = tid & 63;

    // bijective XCD-aware block swizzle (both grids have nwg % 8 == 0)
    const int nwg = (int)(gridDim.x * gridDim.y);
    int bid = (int)blockIdx.y * (int)gridDim.x + (int)blockIdx.x;
    bid = (bid & 7) * (nwg >> 3) + (bid >> 3);
    const int m0 = (bid / (int)gridDim.x) * 128, n0 = (bid % (int)gridDim.x) * 128;

    const int l15 = lane & 15, quad = lane >> 4, q8 = quad * 8;
    const int wr = (w >> 1) * 64, wc = (w & 1) * 64;    // wave's C-quadrant
    const int l8 = lane * 8;                            // u16 offset of lane's 16B
    const int wch = w * 1024;                           // wave's 2KB chunk of 8KB sub-tile

    // panel bases: sub-tile s of this block's panels is 4096 u16 at s*4096
    const u16* pa = A  + ((size_t)(m0 >> 7) * (K / 32) << 12);
    const u16* pb = Bt + ((size_t)(n0 >> 7) * (K / 32) << 12);

    f32x4 acc[4][4];
#pragma unroll
    for (int i = 0; i < 4; ++i)
#pragma unroll
        for (int j = 0; j < 4; ++j) acc[i][j] = (f32x4){0.f, 0.f, 0.f, 0.f};

    const int nSub = K / 32;          // 32-K sub-tiles
    const int nOut = nSub / 2;        // wait-periods
    // prologue: subs 0..3 into bufs 0..3, oldest-first (16 DMAs in flight)
#pragma unroll
    for (int s = 0; s < 4; ++s) {
        const size_t so = (size_t)s << 12;
        gload_lds16(pa + so + wch + l8,       &As[s][wch]);
        gload_lds16(pa + so + wch + 512 + l8, &As[s][wch + 512]);
        gload_lds16(pb + so + wch + l8,       &Bs[s][wch]);
        gload_lds16(pb + so + wch + 512 + l8, &Bs[s][wch + 512]);
    }
    for (int it = 0; it < nOut; ++it) {
        const int s0 = 2 * it, cb0 = s0 & 3, cb1 = (s0 + 1) & 3;
        asm volatile("s_waitcnt vmcnt(8)" ::: "memory");   // subs s0,s0+1 done
        asm volatile("s_barrier" ::: "memory");            // ..for all waves
        bf16x8 a0[4], a1[4], b0[4], b1[4];
#pragma unroll
        for (int t = 0; t < 4; ++t) {
            a0[t] = *(const bf16x8*)&As[cb0][(wr + t * 16 + l15) * 32 + q8];
            b0[t] = *(const bf16x8*)&Bs[cb0][(wc + t * 16 + l15) * 32 + q8];
            a1[t] = *(const bf16x8*)&As[cb1][(wr + t * 16 + l15) * 32 + q8];
            b1[t] = *(const bf16x8*)&Bs[cb1][(wc + t * 16 + l15) * 32 + q8];
        }
        asm volatile("s_waitcnt lgkmcnt(0)" ::: "memory"); // reads in regs
        asm volatile("s_barrier" ::: "memory");            // all waves consumed bufs
        {
            const int sp0 = s0 + 4, sp1 = s0 + 5;
            const size_t k0 = (size_t)((sp0 < nSub) ? sp0 : 0) << 12;  // wrap: dummy
            const size_t k1 = (size_t)((sp1 < nSub) ? sp1 : 0) << 12;
            gload_lds16(pa + k0 + wch + l8,       &As[cb0][wch]);
            gload_lds16(pa + k0 + wch + 512 + l8, &As[cb0][wch + 512]);
            gload_lds16(pb + k0 + wch + l8,       &Bs[cb0][wch]);
            gload_lds16(pb + k0 + wch + 512 + l8, &Bs[cb0][wch + 512]);
            gload_lds16(pa + k1 + wch + l8,       &As[cb1][wch]);
            gload_lds16(pa + k1 + wch + 512 + l8, &As[cb1][wch + 512]);
            gload_lds16(pb + k1 + wch + l8,       &Bs[cb1][wch]);
            gload_lds16(pb + k1 + wch + 512 + l8, &Bs[cb1][wch + 512]);
        }
#pragma unroll
        for (int i = 0; i < 4; ++i)
#pragma unroll
            for (int j = 0; j < 4; ++j) {
                acc[i][j] = __builtin_amdgcn_mfma_f32_16x16x32_bf16(a0[i], b0[j], acc[i][j], 0, 0, 0);
                acc[i][j] = __builtin_amdgcn_mfma_f32_16x16x32_bf16(a1[i], b1[j], acc[i][j], 0, 0, 0);
            }
    }

    if (MODE == 0) {
        float* C = (float*)Cout;
#pragma unroll
        for (int i = 0; i < 4; ++i)
#pragma unroll
            for (int j = 0; j < 4; ++j)
#pragma unroll
                for (int r = 0; r < 4; ++r)
                    C[(size_t)(m0 + wr + i * 16 + quad * 4 + r) * N + n0 + wc + j * 16 + l15] = acc[i][j][r];
    } else {
        __syncthreads();                       // loop done everywhere; LDS reusable
        u16* O = (u16*)Cout;
        const int vc0 = n0 + wc;               // wave's first output column
        if (vc0 < 2560) {                      // Q or K region: RoPE + row store
            const float scl = (vc0 < 2048) ? QSCALE : 1.0f;   // q only
            const int odd = l15 & 1;
#pragma unroll
            for (int i = 0; i < 4; ++i)
#pragma unroll
                for (int j = 0; j < 4; ++j)
#pragma unroll
                    for (int r = 0; r < 4; ++r) {
                        const int row = m0 + wr + i * 16 + quad * 4 + r;
                        const int col = vc0 + j * 16 + l15;
                        float v = acc[i][j][r];
                        const int i2 = (j * 16 + l15) >> 1;   // head-dim pair (vc0 is 64-aligned)
                        const float c = fc[row * 32 + i2], s = fs[row * 32 + i2];
                        const float p = __shfl_xor(v, 1);
                        float o = (odd ? (p * s + v * c) : (v * c - p * s)) * scl;
                        O[(size_t)row * 3072 + col] = f2bf(o);
                    }
        } else {                               // V region: transpose -> vt via LDS
            u16* ws_ = (w < 2 ? (u16*)As : (u16*)Bs) + (w & 1) * (64 * VT_LDS);
#pragma unroll
            for (int i = 0; i < 4; ++i)
#pragma unroll
                for (int j = 0; j < 4; ++j)
#pragma unroll
                    for (int r = 0; r < 4; ++r)
                        ws_[(j * 16 + l15) * VT_LDS + i * 16 + quad * 4 + r] = f2bf(acc[i][j][r]);
            // ws_ is [64 vcols][64 seq]; read rows coalesced, write vt rows
#pragma unroll
            for (int t = 0; t < 8; ++t) {
                const int vr = t * 8 + (lane >> 3);
                const int c8 = (lane & 7) * 8;
                bf16x8 vv = *(const bf16x8*)&ws_[vr * VT_LDS + c8];
                *(bf16x8*)&vt[(size_t)(vc0 - 2560 + vr) * 2048 + m0 + wr + c8] = vv;
            }
        }
    }
}

// ---------------------------------------------------------------------------
// MFMA flash attention (causal, GQA), exp2 domain. Block = (head, 64 q-rows),
// 4 waves x 16 rows. Staging/pipeline = r5 (proven): double-buffered
// global_load_lds + counted vmcnt + both-sides XOR swizzle.
//
// SWAPPED QK^T (S^T = mfma(K,Q)):
//  * lane holds 16 S-values of ONE q-row (l15); keys kt*16+quad*4+r.
//  * row-max: in-lane fmax tree + 2 cross-quad shuffles.
//  * row-SUM: in-lane f32 adds + the same 2 shuffles; l_run is a SCALAR on
//    the l15 side (no per-iteration cross-side gathers; one 4-shuffle gather
//    of l in the epilogue).
//  * KEY IDENTITY: S^T's D-layout == A-fragment layout of 16x16x16 MFMA
//    over the same 16-key block => P feeds PV with ZERO exchange and NO
//    LDS repack (8 cvt_pk only). PV uses the _1k builtin; V read as b64
//    (conflict-free under same swizzle). Ps LDS deleted.
//  * PV output D has qrow on the quad side (row=quad*4+r, col=d=l15) --
//    same as the r5 O layout, store unchanged. alpha moves l15->quad side
//    via 4 intra-quad shuffles, only on rescale iterations.
//  * T13 defer-max (THR=8 log2-units): skip O-rescale + gathers when
//    __all(mx <= m_run + 8); P bounded by 2^8, fine in bf16.
// ---------------------------------------------------------------------------
__global__ __launch_bounds__(256) void attn_mfma_kernel(
    const u16* __restrict__ qkv,  // [2048][3072] bf16: q|k|v
    const u16* __restrict__ vt,   // [512][2048] bf16 (V^T)
    u16* __restrict__ ab)         // panel-layout bf16 [16][64][128][32]
{
    __shared__ __align__(16) u16 Ks[2][64 * 64];   // linear, swizzled content
    __shared__ __align__(16) u16 Vs[2][64 * 64];

    const int h = blockIdx.x;
    const int tile = (int)gridDim.y - 1 - (int)blockIdx.y;  // big tiles first
    const int gkv = h >> 2;
    const int tid = threadIdx.x;
    const int w = tid >> 6, lane = tid & 63;
    const int l15 = lane & 15, quad = lane >> 4;
    const int q0 = tile * 64 + w * 16;

    // staging geometry (r5): wave w stages rows [w*16, w*16+16) of K and V.
    const int srow = lane >> 3, schunk = lane & 7;
    const int r0_ = w * 16 + srow, r1_ = w * 16 + 8 + srow;
    const int c0_ = (schunk ^ (r0_ & 7)) * 8, c1_ = (schunk ^ (r1_ & 7)) * 8;
    const u16* kbase = qkv + 2048 + gkv * HD;          // + (key0+row)*3072 + chunk
    const u16* vbase = vt + (size_t)gkv * HD * 2048;   // + row*2048 + key0 + chunk

    bf16x8 qa[2];
    {
        const u16* qrow = qkv + (size_t)(q0 + l15) * 3072 + h * HD + quad * 8;
        qa[0] = *(const bf16x8*)(qrow);
        qa[1] = *(const bf16x8*)(qrow + 32);
    }
    f32x4 O[4];
#pragma unroll
    for (int i = 0; i < 4; ++i) O[i] = (f32x4){0.f, 0.f, 0.f, 0.f};
    float m_run = -1e30f;      // softmax side: row l15
    float l_run = 0.f;         // softmax side: row l15 (scalar!)

    // prologue: tile 0 into buf 0 (4 DMAs/wave)
    gload_lds16(kbase + (size_t)r0_ * 3072 + c0_, &Ks[0][(w * 16) * 64]);
    gload_lds16(kbase + (size_t)r1_ * 3072 + c1_, &Ks[0][(w * 16 + 8) * 64]);
    gload_lds16(vbase + (size_t)r0_ * 2048 + c0_, &Vs[0][(w * 16) * 64]);
    gload_lds16(vbase + (size_t)r1_ * 2048 + c1_, &Vs[0][(w * 16 + 8) * 64]);

    for (int c = 0; c <= tile; ++c) {
        const int cb = c & 1, nb = cb ^ 1;
        const int kn = (c < tile ? c + 1 : tile) * 64;   // clamp: dummy re-stage
        gload_lds16(kbase + (size_t)(kn + r0_) * 3072 + c0_, &Ks[nb][(w * 16) * 64]);
        gload_lds16(kbase + (size_t)(kn + r1_) * 3072 + c1_, &Ks[nb][(w * 16 + 8) * 64]);
        gload_lds16(vbase + (size_t)r0_ * 2048 + kn + c0_,   &Vs[nb][(w * 16) * 64]);
        gload_lds16(vbase + (size_t)r1_ * 2048 + kn + c1_,   &Vs[nb][(w * 16 + 8) * 64]);
        asm volatile("s_waitcnt vmcnt(4)" ::: "memory");   // tile c's 4 done
        asm volatile("s_barrier" ::: "memory");            // ..for all waves

        // S^T = K Q^T (log2 domain): s[kt][r] -> key=kt*16+quad*4+r, qrow=l15
        f32x4 s[4];
        __builtin_amdgcn_s_setprio(1);
#pragma unroll
        for (int kt = 0; kt < 4; ++kt) {
            const int kr = kt * 16 + l15, kx = (kr & 7);
            bf16x8 b0 = *(const bf16x8*)&Ks[cb][kr * 64 + ((quad ^ kx) * 8)];
            bf16x8 b1 = *(const bf16x8*)&Ks[cb][kr * 64 + (((quad + 4) ^ kx) * 8)];
            f32x4 t = (f32x4){0.f, 0.f, 0.f, 0.f};
            t = __builtin_amdgcn_mfma_f32_16x16x32_bf16(b0, qa[0], t, 0, 0, 0);  // swapped args
            t = __builtin_amdgcn_mfma_f32_16x16x32_bf16(b1, qa[1], t, 0, 0, 0);
            s[kt] = t;
        }
        __builtin_amdgcn_s_setprio(0);
        if (c == tile) {   // diagonal chunk causal mask: key_local > qrow_local
#pragma unroll
            for (int kt = 0; kt < 4; ++kt)
#pragma unroll
                for (int r = 0; r < 4; ++r)
                    if (kt * 16 + quad * 4 + r > w * 16 + l15) s[kt][r] = -1e30f;
        }
        // row max: in-lane tree + cross-quad butterfly (lanes l, l^16, l^32, l^48)
        float mx = fmaxf(fmaxf(fmaxf(s[0][0], s[0][1]), fmaxf(s[0][2], s[0][3])),
                         fmaxf(fmaxf(s[1][0], s[1][1]), fmaxf(s[1][2], s[1][3])));
        mx = fmaxf(mx, fmaxf(fmaxf(fmaxf(s[2][0], s[2][1]), fmaxf(s[2][2], s[2][3])),
                             fmaxf(fmaxf(s[3][0], s[3][1]), fmaxf(s[3][2], s[3][3]))));
        mx = fmaxf(mx, __shfl_xor(mx, 16));
        mx = fmaxf(mx, __shfl_xor(mx, 32));
        // defer-max (T13): only rescale when some row grew by > 8 (log2)
        const bool resc = !__all(mx <= m_run + 8.f);
        float aL = 1.f;
        if (resc) {
            const float mn = fmaxf(m_run, mx);
            aL = exp2f(m_run - mn);
            m_run = mn;
        }
#pragma unroll
        for (int kt = 0; kt < 4; ++kt)
#pragma unroll
            for (int r = 0; r < 4; ++r) s[kt][r] = exp2f(s[kt][r] - m_run);
        // row sum: in-lane f32 adds + cross-quad butterfly (l15 side, scalar)
        float rsum = 0.f;
#pragma unroll
        for (int kt = 0; kt < 4; ++kt)
#pragma unroll
            for (int r = 0; r < 4; ++r) rsum += s[kt][r];
        rsum += __shfl_xor(rsum, 16);
        rsum += __shfl_xor(rsum, 32);
        l_run = resc ? (l_run * aL + rsum) : (l_run + rsum);
        // pack P to bf16 A-fragments (no exchange: S^T D-layout == A16 layout)
        bf16x4 pbf[4];
#pragma unroll
        for (int kt = 0; kt < 4; ++kt) {
            unsigned int lo, hi;
            asm("v_cvt_pk_bf16_f32 %0, %1, %2" : "=v"(lo) : "v"(s[kt][0]), "v"(s[kt][1]));
            asm("v_cvt_pk_bf16_f32 %0, %1, %2" : "=v"(hi) : "v"(s[kt][2]), "v"(s[kt][3]));
            union { unsigned int u[2]; bf16x4 v; } cv;
            cv.u[0] = lo; cv.u[1] = hi;
            pbf[kt] = cv.v;
        }
        // O rescale (quad side): alpha for qrow=quad*4+r lives at lane quad*20+r
        if (resc) {
#pragma unroll
            for (int r = 0; r < 4; ++r) {
                const float aQ = __shfl(aL, (quad << 4) + (quad << 2) + r);
                O[0][r] *= aQ; O[1][r] *= aQ; O[2][r] *= aQ; O[3][r] *= aQ;
            }
        }
        // O += P V via the 16x16x16 builtin: V^T b64 reads (swizzle-consistent)
        __builtin_amdgcn_s_setprio(1);
#pragma unroll
        for (int dt = 0; dt < 4; ++dt) {
            const int vr = dt * 16 + l15, vx = (vr & 7);
#pragma unroll
            for (int kt = 0; kt < 4; ++kt) {
                bf16x4 vf = *(const bf16x4*)&Vs[cb][vr * 64 +
                    (((2 * kt + (quad >> 1)) ^ vx) << 3) + ((quad & 1) << 2)];
                O[dt] = mfma16(pbf[kt], vf, O[dt]);
            }
        }
        __builtin_amdgcn_s_setprio(0);
        asm volatile("s_barrier" ::: "memory");            // all waves done reading buf cb
    }
#pragma unroll
    for (int r = 0; r < 4; ++r) {
        // l for qrow=quad*4+r lives at lane quad*20+r (l15 side -> quad side)
        const float lq = __shfl(l_run, (quad << 4) + (quad << 2) + r);
        const float inv = 1.0f / lq;
        const int q = q0 + quad * 4 + r;
        const int pbase = ((q >> 7) << 18) + ((q & 127) << 5);   // 32-bit panel math
#pragma unroll
        for (int dt = 0; dt < 4; ++dt) {
            const int col = h * HD + dt * 16 + l15;
            ab[pbase + ((col >> 5) << 12) + (col & 31)] = f2bf(O[dt][r] * inv);
        }
    }
}

// ---------------------------------------------------------------------------
extern "C" void kernel_launch(void* const* d_in, const int* in_sizes, int n_in,
                              void* d_out, int out_size, void* d_ws, size_t ws_size,
                              hipStream_t stream)
{
    const float* x  = (const float*)d_in[0];
    const float* wq = (const float*)d_in[1];
    const float* wk = (const float*)d_in[2];
    const float* wv = (const float*)d_in[3];
    const float* wo = (const float*)d_in[4];
    const float* fc = (const float*)d_in[5];
    const float* fs = (const float*)d_in[6];
    // d_in[7] = mask: unused (hard causal == -1e9 additive path in fp32)
    float* out = (float*)d_out;

    // Workspace 50 MB:
    // xb 8MB | wqkvT 12MB | woT 8MB | qkv_bf 12MB | vt 2MB | ab 8MB
    // xb, wqkvT, woT, ab are PANEL layout; qkv_bf, vt plain.
    u16* xb     = (u16*)d_ws;
    u16* wqkvT  = xb     + (size_t)2048 * 2048;
    u16* woT    = wqkvT  + (size_t)3072 * 2048;
    u16* qkv_bf = woT    + (size_t)2048 * 2048;
    u16* vt     = qkv_bf + (size_t)2048 * 3072;
    u16* ab     = vt     + (size_t)512 * 2048;

    // prep: 4 weight transposes + x cast in one dispatch (panel outputs)
    prep_kernel<<<dim3(64, 64, 5), 256, 0, stream>>>(x, xb, wq, wk, wv, wo, wqkvT, woT);

    // QKV projection + fused RoPE/scale/bf16 epilogue + V-transpose -> vt
    gemm4w_kernel<1><<<dim3(3072 / 128, 2048 / 128), 256, 0, stream>>>(
        xb, wqkvT, qkv_bf, 3072, 2048, fc, fs, vt);

    attn_mfma_kernel<<<dim3(NH, L / 64), 256, 0, stream>>>(qkv_bf, vt, ab);

    // out projection -> fp32 output
    gemm4w_kernel<0><<<dim3(2048 / 128, 2048 / 128), 256, 0, stream>>>(
        ab, woT, out, 2048, 2048, nullptr, nullptr, nullptr);
}

// Round 9
// 244.144 us; speedup vs baseline: 1.3115x; 1.0047x over previous
//
#include <hip/hip_runtime.h>
#include <hip/hip_bf16.h>

#define L 2048
#define D 2048
#define NH 32
#define NKV 8
#define HD 64

typedef unsigned short u16;
typedef __attribute__((ext_vector_type(8))) short bf16x8;   // 8 bf16 in 4 VGPRs
typedef __attribute__((ext_vector_type(4))) short bf16x4;   // 4 bf16 in 2 VGPRs
typedef __attribute__((ext_vector_type(4))) float f32x4;

#define QSCALE 0.1803368801f   // 0.125 * log2(e): S comes out in log2 domain

// 16x16x16 bf16 MFMA (K=16): the _1k builtin, called directly (r8-proven).
__device__ __forceinline__ f32x4 mfma16(bf16x4 a, bf16x4 b, f32x4 c) {
    return __builtin_amdgcn_mfma_f32_16x16x16bf16_1k(a, b, c, 0, 0, 0);
}

// Panel layout for GEMM operands: [dim0/128][k/32][128][32] (u16), so one
// 128x32 sub-tile = 8KB contiguous.
#define PANEL_OFF(d0, k) ((((size_t)((d0) >> 7) * 64 + ((k) >> 5)) << 12) + (((d0) & 127) << 5) + ((k) & 31))

__device__ __forceinline__ u16 f2bf(float x) {
    __hip_bfloat16 b = __float2bfloat16(x);
    return *reinterpret_cast<u16*>(&b);
}

// Async global->LDS, 16B per lane. Global src address is PER-LANE; LDS dest
// is wave-uniform base + lane*16.
__device__ __forceinline__ void gload_lds16(const void* g, void* l) {
    __builtin_amdgcn_global_load_lds(
        (const __attribute__((address_space(1))) unsigned int*)g,
        (__attribute__((address_space(3))) unsigned int*)l, 16, 0, 0);
}

// ---------------------------------------------------------------------------
// Fused prep: z=0..3 weight transposes fp32 [2048][C] -> bf16 PANEL layout;
// z=4: x fp32->bf16 cast into PANEL layout.  (unchanged from r4/r5)
// ---------------------------------------------------------------------------
__global__ __launch_bounds__(256) void prep_kernel(
    const float* __restrict__ x, u16* __restrict__ xb,
    const float* __restrict__ wq, const float* __restrict__ wk,
    const float* __restrict__ wv, const float* __restrict__ wo,
    u16* __restrict__ wqkvT, u16* __restrict__ woT)
{
    const int z = blockIdx.z;
    if (z == 4) {                                  // cast x -> panels
        int i = (blockIdx.y * 64 + blockIdx.x) * 256 + threadIdx.x;  // float4 idx
        int e = i * 4;
        int row = e >> 11, k0 = e & 2047;          // x is [2048][2048]
        float4 v = ((const float4*)x)[i];
        ushort4 o;
        o.x = f2bf(v.x); o.y = f2bf(v.y); o.z = f2bf(v.z); o.w = f2bf(v.w);
        *(ushort4*)&xb[PANEL_OFF(row, k0)] = o;    // 4 elems same 32-block, 8B aligned
        return;
    }
    const float* src; u16* dst; int C;
    if (z == 0)      { src = wq; dst = wqkvT;                           C = 2048; }
    else if (z == 1) { src = wk; dst = wqkvT + (size_t)2048 * 2048;     C = 512;  }
    else if (z == 2) { src = wv; dst = wqkvT + (size_t)2560 * 2048;     C = 512;  }
    else             { src = wo; dst = woT;                             C = 2048; }
    const int c0 = blockIdx.x * 32;
    if (c0 >= C) return;
    const int r0 = blockIdx.y * 32;
    __shared__ float tile[32][33];
    const int tx = threadIdx.x & 31, ty = threadIdx.x >> 5;
#pragma unroll
    for (int i = 0; i < 32; i += 8)
        tile[ty + i][tx] = src[(size_t)(r0 + ty + i) * C + c0 + tx];
    __syncthreads();
#pragma unroll
    for (int i = 0; i < 32; i += 8) {
        const int n = c0 + ty + i, k = r0 + tx;    // n = output row (weight col), k = contraction
        dst[PANEL_OFF(n, k)] = f2bf(tile[tx][ty + i]);
    }
}

// ---------------------------------------------------------------------------
// 4-wave 128x128 MFMA GEMM on PANEL-layout operands. (unchanged from r4/r5)
// ---------------------------------------------------------------------------
#define VT_LDS 72   // u16 stride for V-transpose scratch (144B, 16B-aligned)

template <int MODE>
__global__ __launch_bounds__(256) void gemm4w_kernel(
    const u16* __restrict__ A, const u16* __restrict__ Bt, void* __restrict__ Cout,
    int N, int K, const float* __restrict__ fc, const float* __restrict__ fs,
    u16* __restrict__ vt)
{
    __shared__ __align__(16) u16 As[4][128 * 32];
    __shared__ __align__(16) u16 Bs[4][128 * 32];
    const int tid = threadIdx.x;
    const int w = tid >> 6, lane = tid & 63;

    // bijective XCD-aware block swizzle (both grids have nwg % 8 == 0)
    const int nwg = (int)(gridDim.x * gridDim.y);
    int bid = (int)blockIdx.y * (int)gridDim.x + (int)blockIdx.x;
    bid = (bid & 7) * (nwg >> 3) + (bid >> 3);
    const int m0 = (bid / (int)gridDim.x) * 128, n0 = (bid % (int)gridDim.x) * 128;

    const int l15 = lane & 15, quad = lane >> 4, q8 = quad * 8;
    const int wr = (w >> 1) * 64, wc = (w & 1) * 64;    // wave's C-quadrant
    const int l8 = lane * 8;                            // u16 offset of lane's 16B
    const int wch = w * 1024;                           // wave's 2KB chunk of 8KB sub-tile

    // panel bases: sub-tile s of this block's panels is 4096 u16 at s*4096
    const u16* pa = A  + ((size_t)(m0 >> 7) * (K / 32) << 12);
    const u16* pb = Bt + ((size_t)(n0 >> 7) * (K / 32) << 12);

    f32x4 acc[4][4];
#pragma unroll
    for (int i = 0; i < 4; ++i)
#pragma unroll
        for (int j = 0; j < 4; ++j) acc[i][j] = (f32x4){0.f, 0.f, 0.f, 0.f};

    const int nSub = K / 32;          // 32-K sub-tiles
    const int nOut = nSub / 2;        // wait-periods
    // prologue: subs 0..3 into bufs 0..3, oldest-first (16 DMAs in flight)
#pragma unroll
    for (int s = 0; s < 4; ++s) {
        const size_t so = (size_t)s << 12;
        gload_lds16(pa + so + wch + l8,       &As[s][wch]);
        gload_lds16(pa + so + wch + 512 + l8, &As[s][wch + 512]);
        gload_lds16(pb + so + wch + l8,       &Bs[s][wch]);
        gload_lds16(pb + so + wch + 512 + l8, &Bs[s][wch + 512]);
    }
    for (int it = 0; it < nOut; ++it) {
        const int s0 = 2 * it, cb0 = s0 & 3, cb1 = (s0 + 1) & 3;
        asm volatile("s_waitcnt vmcnt(8)" ::: "memory");   // subs s0,s0+1 done
        asm volatile("s_barrier" ::: "memory");            // ..for all waves
        bf16x8 a0[4], a1[4], b0[4], b1[4];
#pragma unroll
        for (int t = 0; t < 4; ++t) {
            a0[t] = *(const bf16x8*)&As[cb0][(wr + t * 16 + l15) * 32 + q8];
            b0[t] = *(const bf16x8*)&Bs[cb0][(wc + t * 16 + l15) * 32 + q8];
            a1[t] = *(const bf16x8*)&As[cb1][(wr + t * 16 + l15) * 32 + q8];
            b1[t] = *(const bf16x8*)&Bs[cb1][(wc + t * 16 + l15) * 32 + q8];
        }
        asm volatile("s_waitcnt lgkmcnt(0)" ::: "memory"); // reads in regs
        asm volatile("s_barrier" ::: "memory");            // all waves consumed bufs
        {
            const int sp0 = s0 + 4, sp1 = s0 + 5;
            const size_t k0 = (size_t)((sp0 < nSub) ? sp0 : 0) << 12;  // wrap: dummy
            const size_t k1 = (size_t)((sp1 < nSub) ? sp1 : 0) << 12;
            gload_lds16(pa + k0 + wch + l8,       &As[cb0][wch]);
            gload_lds16(pa + k0 + wch + 512 + l8, &As[cb0][wch + 512]);
            gload_lds16(pb + k0 + wch + l8,       &Bs[cb0][wch]);
            gload_lds16(pb + k0 + wch + 512 + l8, &Bs[cb0][wch + 512]);
            gload_lds16(pa + k1 + wch + l8,       &As[cb1][wch]);
            gload_lds16(pa + k1 + wch + 512 + l8, &As[cb1][wch + 512]);
            gload_lds16(pb + k1 + wch + l8,       &Bs[cb1][wch]);
            gload_lds16(pb + k1 + wch + 512 + l8, &Bs[cb1][wch + 512]);
        }
#pragma unroll
        for (int i = 0; i < 4; ++i)
#pragma unroll
            for (int j = 0; j < 4; ++j) {
                acc[i][j] = __builtin_amdgcn_mfma_f32_16x16x32_bf16(a0[i], b0[j], acc[i][j], 0, 0, 0);
                acc[i][j] = __builtin_amdgcn_mfma_f32_16x16x32_bf16(a1[i], b1[j], acc[i][j], 0, 0, 0);
            }
    }

    if (MODE == 0) {
        float* C = (float*)Cout;
#pragma unroll
        for (int i = 0; i < 4; ++i)
#pragma unroll
            for (int j = 0; j < 4; ++j)
#pragma unroll
                for (int r = 0; r < 4; ++r)
                    C[(size_t)(m0 + wr + i * 16 + quad * 4 + r) * N + n0 + wc + j * 16 + l15] = acc[i][j][r];
    } else {
        __syncthreads();                       // loop done everywhere; LDS reusable
        u16* O = (u16*)Cout;
        const int vc0 = n0 + wc;               // wave's first output column
        if (vc0 < 2560) {                      // Q or K region: RoPE + row store
            const float scl = (vc0 < 2048) ? QSCALE : 1.0f;   // q only
            const int odd = l15 & 1;
#pragma unroll
            for (int i = 0; i < 4; ++i)
#pragma unroll
                for (int j = 0; j < 4; ++j)
#pragma unroll
                    for (int r = 0; r < 4; ++r) {
                        const int row = m0 + wr + i * 16 + quad * 4 + r;
                        const int col = vc0 + j * 16 + l15;
                        float v = acc[i][j][r];
                        const int i2 = (j * 16 + l15) >> 1;   // head-dim pair (vc0 is 64-aligned)
                        const float c = fc[row * 32 + i2], s = fs[row * 32 + i2];
                        const float p = __shfl_xor(v, 1);
                        float o = (odd ? (p * s + v * c) : (v * c - p * s)) * scl;
                        O[(size_t)row * 3072 + col] = f2bf(o);
                    }
        } else {                               // V region: transpose -> vt via LDS
            u16* ws_ = (w < 2 ? (u16*)As : (u16*)Bs) + (w & 1) * (64 * VT_LDS);
#pragma unroll
            for (int i = 0; i < 4; ++i)
#pragma unroll
                for (int j = 0; j < 4; ++j)
#pragma unroll
                    for (int r = 0; r < 4; ++r)
                        ws_[(j * 16 + l15) * VT_LDS + i * 16 + quad * 4 + r] = f2bf(acc[i][j][r]);
            // ws_ is [64 vcols][64 seq]; read rows coalesced, write vt rows
#pragma unroll
            for (int t = 0; t < 8; ++t) {
                const int vr = t * 8 + (lane >> 3);
                const int c8 = (lane & 7) * 8;
                bf16x8 vv = *(const bf16x8*)&ws_[vr * VT_LDS + c8];
                *(bf16x8*)&vt[(size_t)(vc0 - 2560 + vr) * 2048 + m0 + wr + c8] = vv;
            }
        }
    }
}

// ---------------------------------------------------------------------------
// MFMA flash attention (causal, GQA), exp2 domain. Structure = r8 (passing),
// with r9's VALU-count surgery:
//  * LDS read addresses hoisted to 3 per-lane regs (aK, aK2=aK^64, aV);
//    per-tile addressing = 4 XORs (aV ^ kt*32). Everything else (kt/dt/cb)
//    folds into the ds_read 16-bit imm via the 2x-unrolled (cb compile-time)
//    STEP macro. XOR algebra: mul-by-16 distributes over XOR; quad+4 =
//    quad^4; 2kt+qh = 2kt^qh (disjoint bits).
//  * DMA source pointers strength-reduced to constant bumps (clamp removed:
//    final iteration prefetches garbage into allocated workspace, unused).
// ---------------------------------------------------------------------------
#define ATT_STEP(CVAL, CB)                                                     \
    {                                                                          \
        gload_lds16(pk0, &Ks[(CB) ^ 1][(w * 16) * 64]);                        \
        gload_lds16(pk1, &Ks[(CB) ^ 1][(w * 16 + 8) * 64]);                    \
        gload_lds16(pv0, &Vs[(CB) ^ 1][(w * 16) * 64]);                        \
        gload_lds16(pv1, &Vs[(CB) ^ 1][(w * 16 + 8) * 64]);                    \
        pk0 += 64 * 3072; pk1 += 64 * 3072; pv0 += 64; pv1 += 64;              \
        asm volatile("s_waitcnt vmcnt(4)" ::: "memory");                       \
        asm volatile("s_barrier" ::: "memory");                                \
        const char* KB = (const char*)Ks + (CB) * 8192;                        \
        const char* VB = (const char*)Vs + (CB) * 8192;                        \
        f32x4 s[4];                                                            \
        __builtin_amdgcn_s_setprio(1);                                         \
        _Pragma("unroll")                                                      \
        for (int kt = 0; kt < 4; ++kt) {                                       \
            bf16x8 b0 = *(const bf16x8*)(KB + kt * 2048 + aK);                 \
            bf16x8 b1 = *(const bf16x8*)(KB + kt * 2048 + aK2);                \
            f32x4 t = (f32x4){0.f, 0.f, 0.f, 0.f};                             \
            t = __builtin_amdgcn_mfma_f32_16x16x32_bf16(b0, qa[0], t, 0, 0, 0);\
            t = __builtin_amdgcn_mfma_f32_16x16x32_bf16(b1, qa[1], t, 0, 0, 0);\
            s[kt] = t;                                                         \
        }                                                                      \
        __builtin_amdgcn_s_setprio(0);                                         \
        if ((CVAL) == tile) {                                                  \
            _Pragma("unroll")                                                  \
            for (int kt = 0; kt < 4; ++kt)                                     \
                _Pragma("unroll")                                              \
                for (int r = 0; r < 4; ++r)                                    \
                    if (kt * 16 + quad * 4 + r > w * 16 + l15)                 \
                        s[kt][r] = -1e30f;                                     \
        }                                                                      \
        float mx = fmaxf(fmaxf(fmaxf(s[0][0], s[0][1]), fmaxf(s[0][2], s[0][3])), \
                         fmaxf(fmaxf(s[1][0], s[1][1]), fmaxf(s[1][2], s[1][3]))); \
        mx = fmaxf(mx, fmaxf(fmaxf(fmaxf(s[2][0], s[2][1]), fmaxf(s[2][2], s[2][3])), \
                             fmaxf(fmaxf(s[3][0], s[3][1]), fmaxf(s[3][2], s[3][3])))); \
        mx = fmaxf(mx, __shfl_xor(mx, 16));                                    \
        mx = fmaxf(mx, __shfl_xor(mx, 32));                                    \
        const bool resc = !__all(mx <= m_run + 8.f);                           \
        float aL = 1.f;                                                        \
        if (resc) {                                                            \
            const float mn = fmaxf(m_run, mx);                                 \
            aL = exp2f(m_run - mn);                                            \
            m_run = mn;                                                        \
        }                                                                      \
        _Pragma("unroll")                                                      \
        for (int kt = 0; kt < 4; ++kt)                                         \
            _Pragma("unroll")                                                  \
            for (int r = 0; r < 4; ++r) s[kt][r] = exp2f(s[kt][r] - m_run);    \
        float rsum = 0.f;                                                      \
        _Pragma("unroll")                                                      \
        for (int kt = 0; kt < 4; ++kt)                                         \
            _Pragma("unroll")                                                  \
            for (int r = 0; r < 4; ++r) rsum += s[kt][r];                      \
        rsum += __shfl_xor(rsum, 16);                                          \
        rsum += __shfl_xor(rsum, 32);                                          \
        l_run = resc ? (l_run * aL + rsum) : (l_run + rsum);                   \
        bf16x4 pbf[4];                                                         \
        _Pragma("unroll")                                                      \
        for (int kt = 0; kt < 4; ++kt) {                                       \
            unsigned int lo, hi;                                               \
            asm("v_cvt_pk_bf16_f32 %0, %1, %2" : "=v"(lo) : "v"(s[kt][0]), "v"(s[kt][1])); \
            asm("v_cvt_pk_bf16_f32 %0, %1, %2" : "=v"(hi) : "v"(s[kt][2]), "v"(s[kt][3])); \
            union { unsigned int u[2]; bf16x4 v; } cv;                         \
            cv.u[0] = lo; cv.u[1] = hi;                                        \
            pbf[kt] = cv.v;                                                    \
        }                                                                      \
        if (resc) {                                                            \
            _Pragma("unroll")                                                  \
            for (int r = 0; r < 4; ++r) {                                      \
                const float aQ = __shfl(aL, (quad << 4) + (quad << 2) + r);    \
                O[0][r] *= aQ; O[1][r] *= aQ; O[2][r] *= aQ; O[3][r] *= aQ;    \
            }                                                                  \
        }                                                                      \
        __builtin_amdgcn_s_setprio(1);                                         \
        _Pragma("unroll")                                                      \
        for (int kt = 0; kt < 4; ++kt) {                                       \
            const int aVk = aV ^ (kt * 32);                                    \
            _Pragma("unroll")                                                  \
            for (int dt = 0; dt < 4; ++dt) {                                   \
                bf16x4 vf = *(const bf16x4*)(VB + dt * 2048 + aVk);            \
                O[dt] = mfma16(pbf[kt], vf, O[dt]);                            \
            }                                                                  \
        }                                                                      \
        __builtin_amdgcn_s_setprio(0);                                         \
        asm volatile("s_barrier" ::: "memory");                                \
    }

__global__ __launch_bounds__(256) void attn_mfma_kernel(
    const u16* __restrict__ qkv,  // [2048][3072] bf16: q|k|v
    const u16* __restrict__ vt,   // [512][2048] bf16 (V^T)
    u16* __restrict__ ab)         // panel-layout bf16 [16][64][128][32]
{
    __shared__ __align__(16) u16 Ks[2][64 * 64];   // linear, swizzled content
    __shared__ __align__(16) u16 Vs[2][64 * 64];

    const int h = blockIdx.x;
    const int tile = (int)gridDim.y - 1 - (int)blockIdx.y;  // big tiles first
    const int gkv = h >> 2;
    const int tid = threadIdx.x;
    const int w = tid >> 6, lane = tid & 63;
    const int l15 = lane & 15, quad = lane >> 4;
    const int q0 = tile * 64 + w * 16;

    // staging geometry (r5): wave w stages rows [w*16, w*16+16) of K and V.
    const int srow = lane >> 3, schunk = lane & 7;
    const int r0_ = w * 16 + srow, r1_ = r0_ + 8;
    const int c0_ = (schunk ^ (r0_ & 7)) * 8, c1_ = (schunk ^ (r1_ & 7)) * 8;

    // DMA source pointers: point at the NEXT tile to prefetch (tile 1 after
    // prologue); bumped by constant strides each STEP. Final STEP prefetches
    // one tile past the end -- lands in allocated workspace, never consumed.
    const u16* pk0 = qkv + 2048 + gkv * HD + (size_t)r0_ * 3072 + c0_;
    const u16* pk1 = qkv + 2048 + gkv * HD + (size_t)r1_ * 3072 + c1_;
    const u16* pv0 = vt + (size_t)(gkv * HD + r0_) * 2048 + c0_;
    const u16* pv1 = vt + (size_t)(gkv * HD + r1_) * 2048 + c1_;

    // hoisted per-lane LDS byte-address regs (within one 8KB buffer):
    const int kx = l15 & 7;
    const int aK  = l15 * 128 + ((quad ^ kx) * 16);            // K b128, lo half
    const int aK2 = aK ^ 64;                                   // (quad+4)^kx
    const int aV  = l15 * 128 + (((quad >> 1) ^ kx) * 16) + ((quad & 1) * 8);  // V b64, kt=0

    bf16x8 qa[2];
    {
        const u16* qrow = qkv + (size_t)(q0 + l15) * 3072 + h * HD + quad * 8;
        qa[0] = *(const bf16x8*)(qrow);
        qa[1] = *(const bf16x8*)(qrow + 32);
    }
    f32x4 O[4];
#pragma unroll
    for (int i = 0; i < 4; ++i) O[i] = (f32x4){0.f, 0.f, 0.f, 0.f};
    float m_run = -1e30f;      // softmax side: row l15
    float l_run = 0.f;         // softmax side: row l15 (scalar)

    // prologue: tile 0 into buf 0 (4 DMAs/wave); then bump to tile 1
    gload_lds16(pk0, &Ks[0][(w * 16) * 64]);
    gload_lds16(pk1, &Ks[0][(w * 16 + 8) * 64]);
    gload_lds16(pv0, &Vs[0][(w * 16) * 64]);
    gload_lds16(pv1, &Vs[0][(w * 16 + 8) * 64]);
    pk0 += 64 * 3072; pk1 += 64 * 3072; pv0 += 64; pv1 += 64;

    for (int c = 0; c <= tile; c += 2) {
        ATT_STEP(c, 0)
        if (c + 1 <= tile) {
            ATT_STEP(c + 1, 1)
        }
    }

#pragma unroll
    for (int r = 0; r < 4; ++r) {
        // l for qrow=quad*4+r lives at lane quad*20+r (l15 side -> quad side)
        const float lq = __shfl(l_run, (quad << 4) + (quad << 2) + r);
        const float inv = 1.0f / lq;
        const int q = q0 + quad * 4 + r;
        const int pbase = ((q >> 7) << 18) + ((q & 127) << 5);   // 32-bit panel math
#pragma unroll
        for (int dt = 0; dt < 4; ++dt) {
            const int col = h * HD + dt * 16 + l15;
            ab[pbase + ((col >> 5) << 12) + (col & 31)] = f2bf(O[dt][r] * inv);
        }
    }
}

// ---------------------------------------------------------------------------
extern "C" void kernel_launch(void* const* d_in, const int* in_sizes, int n_in,
                              void* d_out, int out_size, void* d_ws, size_t ws_size,
                              hipStream_t stream)
{
    const float* x  = (const float*)d_in[0];
    const float* wq = (const float*)d_in[1];
    const float* wk = (const float*)d_in[2];
    const float* wv = (const float*)d_in[3];
    const float* wo = (const float*)d_in[4];
    const float* fc = (const float*)d_in[5];
    const float* fs = (const float*)d_in[6];
    // d_in[7] = mask: unused (hard causal == -1e9 additive path in fp32)
    float* out = (float*)d_out;

    // Workspace 50 MB:
    // xb 8MB | wqkvT 12MB | woT 8MB | qkv_bf 12MB | vt 2MB | ab 8MB
    // xb, wqkvT, woT, ab are PANEL layout; qkv_bf, vt plain.
    u16* xb     = (u16*)d_ws;
    u16* wqkvT  = xb     + (size_t)2048 * 2048;
    u16* woT    = wqkvT  + (size_t)3072 * 2048;
    u16* qkv_bf = woT    + (size_t)2048 * 2048;
    u16* vt     = qkv_bf + (size_t)2048 * 3072;
    u16* ab     = vt     + (size_t)512 * 2048;

    // prep: 4 weight transposes + x cast in one dispatch (panel outputs)
    prep_kernel<<<dim3(64, 64, 5), 256, 0, stream>>>(x, xb, wq, wk, wv, wo, wqkvT, woT);

    // QKV projection + fused RoPE/scale/bf16 epilogue + V-transpose -> vt
    gemm4w_kernel<1><<<dim3(3072 / 128, 2048 / 128), 256, 0, stream>>>(
        xb, wqkvT, qkv_bf, 3072, 2048, fc, fs, vt);

    attn_mfma_kernel<<<dim3(NH, L / 64), 256, 0, stream>>>(qkv_bf, vt, ab);

    // out projection -> fp32 output
    gemm4w_kernel<0><<<dim3(2048 / 128, 2048 / 128), 256, 0, stream>>>(
        ab, woT, out, 2048, 2048, nullptr, nullptr, nullptr);
}